// Round 4
// baseline (510.943 us; speedup 1.0000x reference)
//
#include <hip/hip_runtime.h>

#define N_NODES 100000
#define N_EDGESC 1600000
#define ETOT (N_EDGESC + N_NODES)
#define IN_CH 128
#define HID 64
#define OUTC 40
#define NEG_SLOPE 0.2f
#define SCAN_CHUNK 1024
#define NSCAN_BLOCKS ((N_NODES + SCAN_CHUNK - 1) / SCAN_CHUNK)  // 98
#define SEG_CAP 128
#define BNODES 512                      // nodes per bucket
#define NBUCK ((N_NODES + BNODES - 1) / BNODES)  // 196

// ================= counting sort of edges by dst (node histogram + scan) ========

__global__ __launch_bounds__(256) void hist_kernel(const int* __restrict__ dst,
                                                   int* __restrict__ cnt) {
    int i = blockIdx.x * blockDim.x + threadIdx.x;
    if (i >= ETOT) return;
    int d = (i < N_EDGESC) ? dst[i] : (i - N_EDGESC);
    atomicAdd(&cnt[d], 1);
}

__global__ __launch_bounds__(256) void scanA_kernel(const int* __restrict__ cnt,
                                                    int* __restrict__ off,
                                                    int* __restrict__ blockSum) {
    __shared__ int sdata[256];
    int base = blockIdx.x * SCAN_CHUNK;
    int t = threadIdx.x;
    int c[4];
    int s = 0;
#pragma unroll
    for (int j = 0; j < 4; j++) {
        int idx = base + t * 4 + j;
        c[j] = (idx < N_NODES) ? cnt[idx] : 0;
        s += c[j];
    }
    sdata[t] = s;
    __syncthreads();
    for (int o = 1; o < 256; o <<= 1) {
        int v = (t >= o) ? sdata[t - o] : 0;
        __syncthreads();
        sdata[t] += v;
        __syncthreads();
    }
    int run = sdata[t] - s;
#pragma unroll
    for (int j = 0; j < 4; j++) {
        int idx = base + t * 4 + j;
        if (idx < N_NODES) off[idx] = run;
        run += c[j];
    }
    if (t == 255) blockSum[blockIdx.x] = sdata[255];
}

__global__ void scanB_kernel(int* __restrict__ blockSum) {
    __shared__ int s[128];
    int t = threadIdx.x;
    if (t < NSCAN_BLOCKS) s[t] = blockSum[t];
    __syncthreads();
    if (t == 0) {
        int run = 0;
        for (int i = 0; i < NSCAN_BLOCKS; i++) { int v = s[i]; s[i] = run; run += v; }
    }
    __syncthreads();
    if (t < NSCAN_BLOCKS) blockSum[t] = s[t];
}

// finalize off; also init per-bucket cursors (bcur[b*16] = off[b*BNODES])
__global__ __launch_bounds__(256) void scanC_kernel(int* __restrict__ off,
                                                    const int* __restrict__ blockSum,
                                                    int* __restrict__ bcur) {
    int i = blockIdx.x * blockDim.x + threadIdx.x;
    if (i == 0) off[N_NODES] = ETOT;
    if (i >= N_NODES) return;
    int v = off[i] + blockSum[i >> 10];
    off[i] = v;
    if ((i & (BNODES - 1)) == 0) bcur[(i / BNODES) * 16] = v;
}

// ---- pass 1: bucket edges by dst>>9; payload = (d_loc<<17)|src ----
__global__ __launch_bounds__(256) void bucket1_kernel(const int* __restrict__ src,
                                                      const int* __restrict__ dst,
                                                      int* __restrict__ bcur,
                                                      int* __restrict__ buck) {
    int i = blockIdx.x * blockDim.x + threadIdx.x;
    if (i >= ETOT) return;
    int s, d;
    if (i < N_EDGESC) { s = src[i]; d = dst[i]; } else { s = d = i - N_EDGESC; }
    int b = d / BNODES;
    int pos = atomicAdd(&bcur[b * 16], 1);
    buck[pos] = ((d & (BNODES - 1)) << 17) | s;
}

// ---- pass 2: one block per bucket; LDS per-node cursors; write final ssrc ----
__global__ __launch_bounds__(256) void bucket2_kernel(const int* __restrict__ off,
                                                      const int* __restrict__ buck,
                                                      int* __restrict__ ssrc) {
    __shared__ int lcur[BNODES];
    int b = blockIdx.x;
    int base0 = b * BNODES;
    int nn = min(BNODES, N_NODES - base0);
    for (int j = threadIdx.x; j < nn; j += 256) lcur[j] = off[base0 + j];
    __syncthreads();
    int e0 = off[base0];
    int e1 = off[min(base0 + BNODES, N_NODES)];
    for (int i = e0 + threadIdx.x; i < e1; i += 256) {
        int w = buck[i];
        int s = w & 0x1FFFF;
        int dl = w >> 17;
        int pos = atomicAdd(&lcur[dl], 1);
        ssrc[pos] = s;
    }
}

// ================= GEMMs (thread-per-node, W in LDS broadcast) =================

__global__ __launch_bounds__(256) void gemm1_kernel(
    const float* __restrict__ x, const float* __restrict__ W1,
    const float* __restrict__ a_src, const float* __restrict__ a_dst,
    float* __restrict__ h1, float* __restrict__ als, float* __restrict__ ald) {
    __shared__ float Ws[IN_CH * HID];
    __shared__ float as_s[HID], ad_s[HID];
    for (int v = threadIdx.x; v < IN_CH * HID; v += blockDim.x) Ws[v] = W1[v];
    if (threadIdx.x < HID) { as_s[threadIdx.x] = a_src[threadIdx.x]; ad_s[threadIdx.x] = a_dst[threadIdx.x]; }
    __syncthreads();
    int n = blockIdx.x * blockDim.x + threadIdx.x;
    if (n >= N_NODES) return;

    float acc[HID];
#pragma unroll
    for (int c = 0; c < HID; c++) acc[c] = 0.f;

    const float4* xrow = reinterpret_cast<const float4*>(x + (size_t)n * IN_CH);
#pragma unroll 2
    for (int kq = 0; kq < IN_CH / 4; kq++) {
        float4 xv = xrow[kq];
#pragma unroll
        for (int j = 0; j < 4; j++) {
            float xs = (j == 0) ? xv.x : (j == 1) ? xv.y : (j == 2) ? xv.z : xv.w;
            const float4* wr = reinterpret_cast<const float4*>(&Ws[(kq * 4 + j) * HID]);
#pragma unroll
            for (int cq = 0; cq < HID / 4; cq++) {
                float4 wv = wr[cq];
                acc[cq * 4 + 0] += xs * wv.x;
                acc[cq * 4 + 1] += xs * wv.y;
                acc[cq * 4 + 2] += xs * wv.z;
                acc[cq * 4 + 3] += xs * wv.w;
            }
        }
    }
    float s1 = 0.f, s2 = 0.f;
    float4* hrow = reinterpret_cast<float4*>(h1 + (size_t)n * HID);
#pragma unroll
    for (int cq = 0; cq < HID / 4; cq++) {
        float4 o;
        o.x = acc[cq * 4 + 0]; o.y = acc[cq * 4 + 1]; o.z = acc[cq * 4 + 2]; o.w = acc[cq * 4 + 3];
        hrow[cq] = o;
#pragma unroll
        for (int j = 0; j < 4; j++) {
            s1 += acc[cq * 4 + j] * as_s[cq * 4 + j];
            s2 += acc[cq * 4 + j] * ad_s[cq * 4 + j];
        }
    }
    als[n] = s1;
    ald[n] = s2;
}

__global__ __launch_bounds__(256) void gemm2_kernel(
    const float* __restrict__ hin, const float* __restrict__ W2,
    const float* __restrict__ a_src, const float* __restrict__ a_dst,
    float* __restrict__ h2, float* __restrict__ als, float* __restrict__ ald) {
    __shared__ float Ws[HID * OUTC];
    __shared__ float as_s[OUTC], ad_s[OUTC];
    for (int v = threadIdx.x; v < HID * OUTC; v += blockDim.x) Ws[v] = W2[v];
    if (threadIdx.x < OUTC) { as_s[threadIdx.x] = a_src[threadIdx.x]; ad_s[threadIdx.x] = a_dst[threadIdx.x]; }
    __syncthreads();
    int n = blockIdx.x * blockDim.x + threadIdx.x;
    if (n >= N_NODES) return;

    float acc[OUTC];
#pragma unroll
    for (int c = 0; c < OUTC; c++) acc[c] = 0.f;

    const float4* xrow = reinterpret_cast<const float4*>(hin + (size_t)n * HID);
#pragma unroll 2
    for (int kq = 0; kq < HID / 4; kq++) {
        float4 xv = xrow[kq];
#pragma unroll
        for (int j = 0; j < 4; j++) {
            float xs = (j == 0) ? xv.x : (j == 1) ? xv.y : (j == 2) ? xv.z : xv.w;
            const float4* wr = reinterpret_cast<const float4*>(&Ws[(kq * 4 + j) * OUTC]);
#pragma unroll
            for (int cq = 0; cq < OUTC / 4; cq++) {
                float4 wv = wr[cq];
                acc[cq * 4 + 0] += xs * wv.x;
                acc[cq * 4 + 1] += xs * wv.y;
                acc[cq * 4 + 2] += xs * wv.z;
                acc[cq * 4 + 3] += xs * wv.w;
            }
        }
    }
    float s1 = 0.f, s2 = 0.f;
    float4* hrow = reinterpret_cast<float4*>(h2 + (size_t)n * OUTC);
#pragma unroll
    for (int cq = 0; cq < OUTC / 4; cq++) {
        float4 o;
        o.x = acc[cq * 4 + 0]; o.y = acc[cq * 4 + 1]; o.z = acc[cq * 4 + 2]; o.w = acc[cq * 4 + 3];
        hrow[cq] = o;
#pragma unroll
        for (int j = 0; j < 4; j++) {
            s1 += acc[cq * 4 + j] * as_s[cq * 4 + j];
            s2 += acc[cq * 4 + j] * ad_s[cq * 4 + j];
        }
    }
    als[n] = s1;
    ald[n] = s2;
}

// ================= aggregation: wave per dst node, LDS-staged gather =================
template <int C, bool FINAL>
__global__ __launch_bounds__(256) void agg_kernel(
    const int* __restrict__ off, const int* __restrict__ ssrc,
    const float* __restrict__ als, const float* __restrict__ ald,
    const float* __restrict__ h, const float* __restrict__ bias,
    float* __restrict__ outp) {
    __shared__ int   sS[4][SEG_CAP];
    __shared__ float sW[4][SEG_CAP];
    const int wv = threadIdx.x >> 6;
    const int lane = threadIdx.x & 63;
    const int d = (blockIdx.x * blockDim.x + threadIdx.x) >> 6;
    if (d >= N_NODES) return;
    const int o0 = off[d];
    const int deg = off[d + 1] - o0;
    const float aldd = ald[d];

    // ---- phase A: stage s,e ; segment max ----
    float mloc = -1e30f;
    for (int t = lane; t < deg; t += 64) {
        int s = ssrc[o0 + t];
        float e = als[s] + aldd;
        e = e > 0.f ? e : NEG_SLOPE * e;
        if (t < SEG_CAP) { sS[wv][t] = s; sW[wv][t] = e; }
        mloc = fmaxf(mloc, e);
    }
#pragma unroll
    for (int o = 32; o; o >>= 1) mloc = fmaxf(mloc, __shfl_xor(mloc, o));

    // ---- phase B: w = exp(e-m), stage w ; segment sum ----
    float sloc = 0.f;
    for (int t = lane; t < deg; t += 64) {
        float e;
        if (t < SEG_CAP) e = sW[wv][t];
        else { float ee = als[ssrc[o0 + t]] + aldd; e = ee > 0.f ? ee : NEG_SLOPE * ee; }
        float w = __expf(e - mloc);
        if (t < SEG_CAP) sW[wv][t] = w;
        sloc += w;
    }
#pragma unroll
    for (int o = 32; o; o >>= 1) sloc += __shfl_xor(sloc, o);
    const float inv = 1.0f / (sloc + 1e-16f);

    // ---- phase C: half-wave per edge, float2 per lane, unroll x2 ----
    constexpr int CH2 = C / 2;
    const int half = lane >> 5;
    const int hl = lane & 31;
    float ax = 0.f, ay = 0.f;

    auto fetch_sw = [&](int t, int& s, float& w) {
        if (t < SEG_CAP) { s = sS[wv][t]; w = sW[wv][t]; }
        else {
            s = ssrc[o0 + t];
            float e = als[s] + aldd;
            e = e > 0.f ? e : NEG_SLOPE * e;
            w = __expf(e - mloc);
        }
    };

    int t = half;
    for (; t <= deg - 3; t += 4) {
        int s0, s1; float w0, w1;
        fetch_sw(t, s0, w0);
        fetch_sw(t + 2, s1, w1);
        if (hl < CH2) {
            const float2 h0 = *reinterpret_cast<const float2*>(h + (size_t)s0 * C + 2 * hl);
            const float2 h1 = *reinterpret_cast<const float2*>(h + (size_t)s1 * C + 2 * hl);
            ax += w0 * h0.x + w1 * h1.x;
            ay += w0 * h0.y + w1 * h1.y;
        }
    }
    if (t < deg) {
        int s0; float w0;
        fetch_sw(t, s0, w0);
        if (hl < CH2) {
            const float2 h0 = *reinterpret_cast<const float2*>(h + (size_t)s0 * C + 2 * hl);
            ax += w0 * h0.x;
            ay += w0 * h0.y;
        }
    }
    ax += __shfl_xor(ax, 32);
    ay += __shfl_xor(ay, 32);

    const bool valid = (half == 0) && (hl < CH2);
    if (!FINAL) {
        if (valid) {
            const float2 bb = reinterpret_cast<const float2*>(bias)[hl];
            float2 v;
            v.x = ax * inv + bb.x;
            v.y = ay * inv + bb.y;
            v.x = v.x > 0.f ? v.x : 0.f;
            v.y = v.y > 0.f ? v.y : 0.f;
            *reinterpret_cast<float2*>(outp + (size_t)d * C + 2 * hl) = v;
        }
    } else {
        float vx = 0.f, vy = 0.f, mm = -1e30f;
        if (valid) {
            const float2 bb = reinterpret_cast<const float2*>(bias)[hl];
            vx = ax * inv + bb.x;
            vy = ay * inv + bb.y;
            mm = fmaxf(vx, vy);
        }
#pragma unroll
        for (int o = 32; o; o >>= 1) mm = fmaxf(mm, __shfl_xor(mm, o));
        float ex = valid ? (__expf(vx - mm) + __expf(vy - mm)) : 0.f;
#pragma unroll
        for (int o = 32; o; o >>= 1) ex += __shfl_xor(ex, o);
        if (valid) {
            const float lse = mm + logf(ex);
            float2 v; v.x = vx - lse; v.y = vy - lse;
            *reinterpret_cast<float2*>(outp + (size_t)d * C + 2 * hl) = v;
        }
    }
}

extern "C" void kernel_launch(void* const* d_in, const int* in_sizes, int n_in,
                              void* d_out, int out_size, void* d_ws, size_t ws_size,
                              hipStream_t stream) {
    const float* x   = (const float*)d_in[0];
    const int*   ei  = (const int*)d_in[1];
    const float* W1  = (const float*)d_in[2];
    const float* as1 = (const float*)d_in[3];
    const float* ad1 = (const float*)d_in[4];
    const float* b1  = (const float*)d_in[5];
    const float* W2  = (const float*)d_in[6];
    const float* as2 = (const float*)d_in[7];
    const float* ad2 = (const float*)d_in[8];
    const float* b2  = (const float*)d_in[9];
    float* out = (float*)d_out;

    float* A    = (float*)d_ws;                        // N*64 : buck (sort) -> h1 -> h2
    float* B    = A + (size_t)N_NODES * 64;            // N*64 : layer-1 output / gemm2 input
    float* als  = B + (size_t)N_NODES * 64;            // N
    float* ald  = als + N_NODES;                       // N
    int* cnt    = (int*)(ald + N_NODES);               // N  (degree histogram)
    int* off    = cnt + N_NODES;                       // N+1
    int* blockSum = off + (N_NODES + 1);               // NSCAN_BLOCKS (pad 256)
    int* bcur   = blockSum + 256;                      // NBUCK*16 (64B-padded cursors)
    int* ssrc   = bcur + NBUCK * 16;                   // ETOT
    int* buck   = (int*)A;                             // ETOT, aliases A (used only pre-gemm1)

    const int* srcA = ei;
    const int* dstA = ei + N_EDGESC;

    // ---- build dst-sorted edge structure (shared by both layers) ----
    hipMemsetAsync(cnt, 0, N_NODES * sizeof(int), stream);
    hist_kernel<<<(ETOT + 255) / 256, 256, 0, stream>>>(dstA, cnt);
    scanA_kernel<<<NSCAN_BLOCKS, 256, 0, stream>>>(cnt, off, blockSum);
    scanB_kernel<<<1, 128, 0, stream>>>(blockSum);
    scanC_kernel<<<(N_NODES + 255) / 256, 256, 0, stream>>>(off, blockSum, bcur);
    bucket1_kernel<<<(ETOT + 255) / 256, 256, 0, stream>>>(srcA, dstA, bcur, buck);
    bucket2_kernel<<<NBUCK, 256, 0, stream>>>(off, buck, ssrc);

    // ---- layer 1 ----
    gemm1_kernel<<<(N_NODES + 255) / 256, 256, 0, stream>>>(x, W1, as1, ad1, A, als, ald);
    agg_kernel<HID, false><<<(N_NODES * 64 + 255) / 256, 256, 0, stream>>>(off, ssrc, als, ald, A, b1, B);

    // ---- layer 2 ----
    gemm2_kernel<<<(N_NODES + 255) / 256, 256, 0, stream>>>(B, W2, as2, ad2, A, als, ald);
    agg_kernel<OUTC, true><<<(N_NODES * 64 + 255) / 256, 256, 0, stream>>>(off, ssrc, als, ald, A, b2, out);
}

// Round 5
// 348.970 us; speedup vs baseline: 1.4641x; 1.4641x over previous
//
#include <hip/hip_runtime.h>

#define N_NODES 100000
#define N_EDGESC 1600000
#define ETOT (N_EDGESC + N_NODES)
#define IN_CH 128
#define HID 64
#define OUTC 40
#define NEG_SLOPE 0.2f
#define SCAN_CHUNK 1024
#define NSCAN_BLOCKS ((N_NODES + SCAN_CHUNK - 1) / SCAN_CHUNK)  // 98
#define SEG_CAP 128
#define BNODES 512                                   // nodes per bucket
#define NBUCK ((N_NODES + BNODES - 1) / BNODES)      // 196
#define TILE 8192                                    // edges per bucket1 block
#define EPT (TILE / 256)                             // 32 edges per thread

// ================= counting sort of edges by dst (node histogram + scan) ========

__global__ __launch_bounds__(256) void hist_kernel(const int* __restrict__ dst,
                                                   int* __restrict__ cnt) {
    int i = blockIdx.x * blockDim.x + threadIdx.x;
    if (i >= ETOT) return;
    int d = (i < N_EDGESC) ? dst[i] : (i - N_EDGESC);
    atomicAdd(&cnt[d], 1);
}

__global__ __launch_bounds__(256) void scanA_kernel(const int* __restrict__ cnt,
                                                    int* __restrict__ off,
                                                    int* __restrict__ blockSum) {
    __shared__ int sdata[256];
    int base = blockIdx.x * SCAN_CHUNK;
    int t = threadIdx.x;
    int c[4];
    int s = 0;
#pragma unroll
    for (int j = 0; j < 4; j++) {
        int idx = base + t * 4 + j;
        c[j] = (idx < N_NODES) ? cnt[idx] : 0;
        s += c[j];
    }
    sdata[t] = s;
    __syncthreads();
    for (int o = 1; o < 256; o <<= 1) {
        int v = (t >= o) ? sdata[t - o] : 0;
        __syncthreads();
        sdata[t] += v;
        __syncthreads();
    }
    int run = sdata[t] - s;
#pragma unroll
    for (int j = 0; j < 4; j++) {
        int idx = base + t * 4 + j;
        if (idx < N_NODES) off[idx] = run;
        run += c[j];
    }
    if (t == 255) blockSum[blockIdx.x] = sdata[255];
}

__global__ void scanB_kernel(int* __restrict__ blockSum) {
    __shared__ int s[128];
    int t = threadIdx.x;
    if (t < NSCAN_BLOCKS) s[t] = blockSum[t];
    __syncthreads();
    if (t == 0) {
        int run = 0;
        for (int i = 0; i < NSCAN_BLOCKS; i++) { int v = s[i]; s[i] = run; run += v; }
    }
    __syncthreads();
    if (t < NSCAN_BLOCKS) blockSum[t] = s[t];
}

// finalize off; also init per-bucket cursors (bcur[b*16] = off[b*BNODES])
__global__ __launch_bounds__(256) void scanC_kernel(int* __restrict__ off,
                                                    const int* __restrict__ blockSum,
                                                    int* __restrict__ bcur) {
    int i = blockIdx.x * blockDim.x + threadIdx.x;
    if (i == 0) off[N_NODES] = ETOT;
    if (i >= N_NODES) return;
    int v = off[i] + blockSum[i >> 10];
    off[i] = v;
    if ((i & (BNODES - 1)) == 0) bcur[(i / BNODES) * 16] = v;
}

// ---- pass 1 (v2): block-local LDS binning, one global atomic per (block,bucket),
//      coalesced run output. payload = (d_loc<<17)|src ----
__global__ __launch_bounds__(256) void bucket1_kernel(const int* __restrict__ src,
                                                      const int* __restrict__ dst,
                                                      int* __restrict__ bcur,
                                                      int* __restrict__ buck) {
    __shared__ int hist[256];    // per-bucket count in this tile
    __shared__ int lofs[256];    // inclusive scan of hist
    __shared__ int gbase[256];   // reserved global base per bucket
    __shared__ int cur[256];     // running local cursor per bucket
    __shared__ int stage[TILE];  // 32 KB bucket-sorted payload

    const int t = threadIdx.x;
    const int t0 = blockIdx.x * TILE;
    hist[t] = 0;
    __syncthreads();

    int payload[EPT];
    int bkt[EPT];
#pragma unroll
    for (int j = 0; j < EPT; j++) {
        int i = t0 + j * 256 + t;
        if (i < ETOT) {
            int s, d;
            if (i < N_EDGESC) { s = src[i]; d = dst[i]; } else { s = d = i - N_EDGESC; }
            int b = d / BNODES;
            bkt[j] = b;
            payload[j] = ((d & (BNODES - 1)) << 17) | s;
            atomicAdd(&hist[b], 1);
        } else {
            bkt[j] = -1;
            payload[j] = 0;
        }
    }
    __syncthreads();

    // inclusive scan of hist into lofs
    int hv = hist[t];
    lofs[t] = hv;
    __syncthreads();
    for (int o = 1; o < 256; o <<= 1) {
        int v = (t >= o) ? lofs[t - o] : 0;
        __syncthreads();
        lofs[t] += v;
        __syncthreads();
    }
    // reserve global space; init local cursor to exclusive offset
    int excl = lofs[t] - hv;
    cur[t] = excl;
    if (t < NBUCK && hv > 0) gbase[t] = atomicAdd(&bcur[t * 16], hv);
    __syncthreads();

    // place payloads into bucket-sorted LDS order
#pragma unroll
    for (int j = 0; j < EPT; j++) {
        if (bkt[j] >= 0) {
            int p = atomicAdd(&cur[bkt[j]], 1);
            stage[p] = payload[j];
        }
    }
    __syncthreads();

    // stream out runs: wave wv handles buckets wv, wv+4, ...
    const int wv = t >> 6;
    const int lane = t & 63;
    for (int b = wv; b < NBUCK; b += 4) {
        int cntb = hist[b];
        if (cntb == 0) continue;
        int lo = lofs[b] - cntb;
        int gb = gbase[b];
        for (int k = lane; k < cntb; k += 64) buck[gb + k] = stage[lo + k];
    }
}

// ---- pass 2: one block per bucket; LDS per-node cursors; write final ssrc ----
__global__ __launch_bounds__(256) void bucket2_kernel(const int* __restrict__ off,
                                                      const int* __restrict__ buck,
                                                      int* __restrict__ ssrc) {
    __shared__ int lcur[BNODES];
    int b = blockIdx.x;
    int base0 = b * BNODES;
    int nn = min(BNODES, N_NODES - base0);
    for (int j = threadIdx.x; j < nn; j += 256) lcur[j] = off[base0 + j];
    __syncthreads();
    int e0 = off[base0];
    int e1 = off[min(base0 + BNODES, N_NODES)];
    for (int i = e0 + threadIdx.x; i < e1; i += 256) {
        int w = buck[i];
        int s = w & 0x1FFFF;
        int dl = w >> 17;
        int pos = atomicAdd(&lcur[dl], 1);
        ssrc[pos] = s;
    }
}

// ================= GEMMs (thread-per-node, W in LDS broadcast) =================

__global__ __launch_bounds__(256) void gemm1_kernel(
    const float* __restrict__ x, const float* __restrict__ W1,
    const float* __restrict__ a_src, const float* __restrict__ a_dst,
    float* __restrict__ h1, float* __restrict__ als, float* __restrict__ ald) {
    __shared__ float Ws[IN_CH * HID];
    __shared__ float as_s[HID], ad_s[HID];
    for (int v = threadIdx.x; v < IN_CH * HID; v += blockDim.x) Ws[v] = W1[v];
    if (threadIdx.x < HID) { as_s[threadIdx.x] = a_src[threadIdx.x]; ad_s[threadIdx.x] = a_dst[threadIdx.x]; }
    __syncthreads();
    int n = blockIdx.x * blockDim.x + threadIdx.x;
    if (n >= N_NODES) return;

    float acc[HID];
#pragma unroll
    for (int c = 0; c < HID; c++) acc[c] = 0.f;

    const float4* xrow = reinterpret_cast<const float4*>(x + (size_t)n * IN_CH);
#pragma unroll 2
    for (int kq = 0; kq < IN_CH / 4; kq++) {
        float4 xv = xrow[kq];
#pragma unroll
        for (int j = 0; j < 4; j++) {
            float xs = (j == 0) ? xv.x : (j == 1) ? xv.y : (j == 2) ? xv.z : xv.w;
            const float4* wr = reinterpret_cast<const float4*>(&Ws[(kq * 4 + j) * HID]);
#pragma unroll
            for (int cq = 0; cq < HID / 4; cq++) {
                float4 wv = wr[cq];
                acc[cq * 4 + 0] += xs * wv.x;
                acc[cq * 4 + 1] += xs * wv.y;
                acc[cq * 4 + 2] += xs * wv.z;
                acc[cq * 4 + 3] += xs * wv.w;
            }
        }
    }
    float s1 = 0.f, s2 = 0.f;
    float4* hrow = reinterpret_cast<float4*>(h1 + (size_t)n * HID);
#pragma unroll
    for (int cq = 0; cq < HID / 4; cq++) {
        float4 o;
        o.x = acc[cq * 4 + 0]; o.y = acc[cq * 4 + 1]; o.z = acc[cq * 4 + 2]; o.w = acc[cq * 4 + 3];
        hrow[cq] = o;
#pragma unroll
        for (int j = 0; j < 4; j++) {
            s1 += acc[cq * 4 + j] * as_s[cq * 4 + j];
            s2 += acc[cq * 4 + j] * ad_s[cq * 4 + j];
        }
    }
    als[n] = s1;
    ald[n] = s2;
}

__global__ __launch_bounds__(256) void gemm2_kernel(
    const float* __restrict__ hin, const float* __restrict__ W2,
    const float* __restrict__ a_src, const float* __restrict__ a_dst,
    float* __restrict__ h2, float* __restrict__ als, float* __restrict__ ald) {
    __shared__ float Ws[HID * OUTC];
    __shared__ float as_s[OUTC], ad_s[OUTC];
    for (int v = threadIdx.x; v < HID * OUTC; v += blockDim.x) Ws[v] = W2[v];
    if (threadIdx.x < OUTC) { as_s[threadIdx.x] = a_src[threadIdx.x]; ad_s[threadIdx.x] = a_dst[threadIdx.x]; }
    __syncthreads();
    int n = blockIdx.x * blockDim.x + threadIdx.x;
    if (n >= N_NODES) return;

    float acc[OUTC];
#pragma unroll
    for (int c = 0; c < OUTC; c++) acc[c] = 0.f;

    const float4* xrow = reinterpret_cast<const float4*>(hin + (size_t)n * HID);
#pragma unroll 2
    for (int kq = 0; kq < HID / 4; kq++) {
        float4 xv = xrow[kq];
#pragma unroll
        for (int j = 0; j < 4; j++) {
            float xs = (j == 0) ? xv.x : (j == 1) ? xv.y : (j == 2) ? xv.z : xv.w;
            const float4* wr = reinterpret_cast<const float4*>(&Ws[(kq * 4 + j) * OUTC]);
#pragma unroll
            for (int cq = 0; cq < OUTC / 4; cq++) {
                float4 wv = wr[cq];
                acc[cq * 4 + 0] += xs * wv.x;
                acc[cq * 4 + 1] += xs * wv.y;
                acc[cq * 4 + 2] += xs * wv.z;
                acc[cq * 4 + 3] += xs * wv.w;
            }
        }
    }
    float s1 = 0.f, s2 = 0.f;
    float4* hrow = reinterpret_cast<float4*>(h2 + (size_t)n * OUTC);
#pragma unroll
    for (int cq = 0; cq < OUTC / 4; cq++) {
        float4 o;
        o.x = acc[cq * 4 + 0]; o.y = acc[cq * 4 + 1]; o.z = acc[cq * 4 + 2]; o.w = acc[cq * 4 + 3];
        hrow[cq] = o;
#pragma unroll
        for (int j = 0; j < 4; j++) {
            s1 += acc[cq * 4 + j] * as_s[cq * 4 + j];
            s2 += acc[cq * 4 + j] * ad_s[cq * 4 + j];
        }
    }
    als[n] = s1;
    ald[n] = s2;
}

// ================= aggregation: wave per dst node, LDS-staged gather =================
template <int C, bool FINAL>
__global__ __launch_bounds__(256) void agg_kernel(
    const int* __restrict__ off, const int* __restrict__ ssrc,
    const float* __restrict__ als, const float* __restrict__ ald,
    const float* __restrict__ h, const float* __restrict__ bias,
    float* __restrict__ outp) {
    __shared__ int   sS[4][SEG_CAP];
    __shared__ float sW[4][SEG_CAP];
    const int wv = threadIdx.x >> 6;
    const int lane = threadIdx.x & 63;
    const int d = (blockIdx.x * blockDim.x + threadIdx.x) >> 6;
    if (d >= N_NODES) return;
    const int o0 = off[d];
    const int deg = off[d + 1] - o0;
    const float aldd = ald[d];

    // ---- phase A: stage s,e ; segment max ----
    float mloc = -1e30f;
    for (int t = lane; t < deg; t += 64) {
        int s = ssrc[o0 + t];
        float e = als[s] + aldd;
        e = e > 0.f ? e : NEG_SLOPE * e;
        if (t < SEG_CAP) { sS[wv][t] = s; sW[wv][t] = e; }
        mloc = fmaxf(mloc, e);
    }
#pragma unroll
    for (int o = 32; o; o >>= 1) mloc = fmaxf(mloc, __shfl_xor(mloc, o));

    // ---- phase B: w = exp(e-m), stage w ; segment sum ----
    float sloc = 0.f;
    for (int t = lane; t < deg; t += 64) {
        float e;
        if (t < SEG_CAP) e = sW[wv][t];
        else { float ee = als[ssrc[o0 + t]] + aldd; e = ee > 0.f ? ee : NEG_SLOPE * ee; }
        float w = __expf(e - mloc);
        if (t < SEG_CAP) sW[wv][t] = w;
        sloc += w;
    }
#pragma unroll
    for (int o = 32; o; o >>= 1) sloc += __shfl_xor(sloc, o);
    const float inv = 1.0f / (sloc + 1e-16f);

    // ---- phase C: half-wave per edge, float2 per lane, unroll x2 ----
    constexpr int CH2 = C / 2;
    const int half = lane >> 5;
    const int hl = lane & 31;
    float ax = 0.f, ay = 0.f;

    auto fetch_sw = [&](int t, int& s, float& w) {
        if (t < SEG_CAP) { s = sS[wv][t]; w = sW[wv][t]; }
        else {
            s = ssrc[o0 + t];
            float e = als[s] + aldd;
            e = e > 0.f ? e : NEG_SLOPE * e;
            w = __expf(e - mloc);
        }
    };

    int t = half;
    for (; t <= deg - 3; t += 4) {
        int s0, s1; float w0, w1;
        fetch_sw(t, s0, w0);
        fetch_sw(t + 2, s1, w1);
        if (hl < CH2) {
            const float2 h0 = *reinterpret_cast<const float2*>(h + (size_t)s0 * C + 2 * hl);
            const float2 h1 = *reinterpret_cast<const float2*>(h + (size_t)s1 * C + 2 * hl);
            ax += w0 * h0.x + w1 * h1.x;
            ay += w0 * h0.y + w1 * h1.y;
        }
    }
    if (t < deg) {
        int s0; float w0;
        fetch_sw(t, s0, w0);
        if (hl < CH2) {
            const float2 h0 = *reinterpret_cast<const float2*>(h + (size_t)s0 * C + 2 * hl);
            ax += w0 * h0.x;
            ay += w0 * h0.y;
        }
    }
    ax += __shfl_xor(ax, 32);
    ay += __shfl_xor(ay, 32);

    const bool valid = (half == 0) && (hl < CH2);
    if (!FINAL) {
        if (valid) {
            const float2 bb = reinterpret_cast<const float2*>(bias)[hl];
            float2 v;
            v.x = ax * inv + bb.x;
            v.y = ay * inv + bb.y;
            v.x = v.x > 0.f ? v.x : 0.f;
            v.y = v.y > 0.f ? v.y : 0.f;
            *reinterpret_cast<float2*>(outp + (size_t)d * C + 2 * hl) = v;
        }
    } else {
        float vx = 0.f, vy = 0.f, mm = -1e30f;
        if (valid) {
            const float2 bb = reinterpret_cast<const float2*>(bias)[hl];
            vx = ax * inv + bb.x;
            vy = ay * inv + bb.y;
            mm = fmaxf(vx, vy);
        }
#pragma unroll
        for (int o = 32; o; o >>= 1) mm = fmaxf(mm, __shfl_xor(mm, o));
        float ex = valid ? (__expf(vx - mm) + __expf(vy - mm)) : 0.f;
#pragma unroll
        for (int o = 32; o; o >>= 1) ex += __shfl_xor(ex, o);
        if (valid) {
            const float lse = mm + logf(ex);
            float2 v; v.x = vx - lse; v.y = vy - lse;
            *reinterpret_cast<float2*>(outp + (size_t)d * C + 2 * hl) = v;
        }
    }
}

extern "C" void kernel_launch(void* const* d_in, const int* in_sizes, int n_in,
                              void* d_out, int out_size, void* d_ws, size_t ws_size,
                              hipStream_t stream) {
    const float* x   = (const float*)d_in[0];
    const int*   ei  = (const int*)d_in[1];
    const float* W1  = (const float*)d_in[2];
    const float* as1 = (const float*)d_in[3];
    const float* ad1 = (const float*)d_in[4];
    const float* b1  = (const float*)d_in[5];
    const float* W2  = (const float*)d_in[6];
    const float* as2 = (const float*)d_in[7];
    const float* ad2 = (const float*)d_in[8];
    const float* b2  = (const float*)d_in[9];
    float* out = (float*)d_out;

    float* A    = (float*)d_ws;                        // N*64 : buck (sort) -> h1 -> h2
    float* B    = A + (size_t)N_NODES * 64;            // N*64 : layer-1 output / gemm2 input
    float* als  = B + (size_t)N_NODES * 64;            // N
    float* ald  = als + N_NODES;                       // N
    int* cnt    = (int*)(ald + N_NODES);               // N  (degree histogram)
    int* off    = cnt + N_NODES;                       // N+1
    int* blockSum = off + (N_NODES + 1);               // NSCAN_BLOCKS (pad 256)
    int* bcur   = blockSum + 256;                      // NBUCK*16 (64B-padded cursors)
    int* ssrc   = bcur + NBUCK * 16;                   // ETOT
    int* buck   = (int*)A;                             // ETOT, aliases A (used only pre-gemm1)

    const int* srcA = ei;
    const int* dstA = ei + N_EDGESC;

    // ---- build dst-sorted edge structure (shared by both layers) ----
    hipMemsetAsync(cnt, 0, N_NODES * sizeof(int), stream);
    hist_kernel<<<(ETOT + 255) / 256, 256, 0, stream>>>(dstA, cnt);
    scanA_kernel<<<NSCAN_BLOCKS, 256, 0, stream>>>(cnt, off, blockSum);
    scanB_kernel<<<1, 128, 0, stream>>>(blockSum);
    scanC_kernel<<<(N_NODES + 255) / 256, 256, 0, stream>>>(off, blockSum, bcur);
    bucket1_kernel<<<(ETOT + TILE - 1) / TILE, 256, 0, stream>>>(srcA, dstA, bcur, buck);
    bucket2_kernel<<<NBUCK, 256, 0, stream>>>(off, buck, ssrc);

    // ---- layer 1 ----
    gemm1_kernel<<<(N_NODES + 255) / 256, 256, 0, stream>>>(x, W1, as1, ad1, A, als, ald);
    agg_kernel<HID, false><<<(N_NODES * 64 + 255) / 256, 256, 0, stream>>>(off, ssrc, als, ald, A, b1, B);

    // ---- layer 2 ----
    gemm2_kernel<<<(N_NODES + 255) / 256, 256, 0, stream>>>(B, W2, as2, ad2, A, als, ald);
    agg_kernel<OUTC, true><<<(N_NODES * 64 + 255) / 256, 256, 0, stream>>>(off, ssrc, als, ald, A, b2, out);
}

// Round 7
// 321.146 us; speedup vs baseline: 1.5910x; 1.0866x over previous
//
#include <hip/hip_runtime.h>
#include <hip/hip_fp16.h>

#define N_NODES 100000
#define N_EDGESC 1600000
#define ETOT (N_EDGESC + N_NODES)
#define IN_CH 128
#define HID 64
#define OUTC 40
#define NEG_SLOPE 0.2f
#define SCAN_CHUNK 1024
#define NSCAN_BLOCKS ((N_NODES + SCAN_CHUNK - 1) / SCAN_CHUNK)  // 98
#define SEG_CAP 128
#define BNODES 512                                   // nodes per bucket
#define NBUCK ((N_NODES + BNODES - 1) / BNODES)      // 196
#define TILE 8192                                    // edges per bucket1 block
#define EPT (TILE / 256)                             // 32 edges per thread

// ================= counting sort of edges by dst (node histogram + scan) ========

__global__ __launch_bounds__(256) void hist_kernel(const int* __restrict__ dst,
                                                   int* __restrict__ cnt) {
    int i = blockIdx.x * blockDim.x + threadIdx.x;
    if (i >= ETOT) return;
    int d = (i < N_EDGESC) ? dst[i] : (i - N_EDGESC);
    atomicAdd(&cnt[d], 1);
}

__global__ __launch_bounds__(256) void scanA_kernel(const int* __restrict__ cnt,
                                                    int* __restrict__ off,
                                                    int* __restrict__ blockSum) {
    __shared__ int sdata[256];
    int base = blockIdx.x * SCAN_CHUNK;
    int t = threadIdx.x;
    int c[4];
    int s = 0;
#pragma unroll
    for (int j = 0; j < 4; j++) {
        int idx = base + t * 4 + j;
        c[j] = (idx < N_NODES) ? cnt[idx] : 0;
        s += c[j];
    }
    sdata[t] = s;
    __syncthreads();
    for (int o = 1; o < 256; o <<= 1) {
        int v = (t >= o) ? sdata[t - o] : 0;
        __syncthreads();
        sdata[t] += v;
        __syncthreads();
    }
    int run = sdata[t] - s;
#pragma unroll
    for (int j = 0; j < 4; j++) {
        int idx = base + t * 4 + j;
        if (idx < N_NODES) off[idx] = run;
        run += c[j];
    }
    if (t == 255) blockSum[blockIdx.x] = sdata[255];
}

__global__ void scanB_kernel(int* __restrict__ blockSum) {
    __shared__ int s[128];
    int t = threadIdx.x;
    if (t < NSCAN_BLOCKS) s[t] = blockSum[t];
    __syncthreads();
    if (t == 0) {
        int run = 0;
        for (int i = 0; i < NSCAN_BLOCKS; i++) { int v = s[i]; s[i] = run; run += v; }
    }
    __syncthreads();
    if (t < NSCAN_BLOCKS) blockSum[t] = s[t];
}

__global__ __launch_bounds__(256) void scanC_kernel(int* __restrict__ off,
                                                    const int* __restrict__ blockSum,
                                                    int* __restrict__ bcur) {
    int i = blockIdx.x * blockDim.x + threadIdx.x;
    if (i == 0) off[N_NODES] = ETOT;
    if (i >= N_NODES) return;
    int v = off[i] + blockSum[i >> 10];
    off[i] = v;
    if ((i & (BNODES - 1)) == 0) bcur[(i / BNODES) * 16] = v;
}

// ---- pass 1: block-local LDS binning, one global atomic per (block,bucket) ----
__global__ __launch_bounds__(256) void bucket1_kernel(const int* __restrict__ src,
                                                      const int* __restrict__ dst,
                                                      int* __restrict__ bcur,
                                                      int* __restrict__ buck) {
    __shared__ int hist[256];
    __shared__ int lofs[256];
    __shared__ int gbase[256];
    __shared__ int cur[256];
    __shared__ int stage[TILE];

    const int t = threadIdx.x;
    const int t0 = blockIdx.x * TILE;
    hist[t] = 0;
    __syncthreads();

    int payload[EPT];
    int bkt[EPT];
#pragma unroll
    for (int j = 0; j < EPT; j++) {
        int i = t0 + j * 256 + t;
        if (i < ETOT) {
            int s, d;
            if (i < N_EDGESC) { s = src[i]; d = dst[i]; } else { s = d = i - N_EDGESC; }
            int b = d / BNODES;
            bkt[j] = b;
            payload[j] = ((d & (BNODES - 1)) << 17) | s;
            atomicAdd(&hist[b], 1);
        } else {
            bkt[j] = -1;
            payload[j] = 0;
        }
    }
    __syncthreads();

    int hv = hist[t];
    lofs[t] = hv;
    __syncthreads();
    for (int o = 1; o < 256; o <<= 1) {
        int v = (t >= o) ? lofs[t - o] : 0;
        __syncthreads();
        lofs[t] += v;
        __syncthreads();
    }
    int excl = lofs[t] - hv;
    cur[t] = excl;
    if (t < NBUCK && hv > 0) gbase[t] = atomicAdd(&bcur[t * 16], hv);
    __syncthreads();

#pragma unroll
    for (int j = 0; j < EPT; j++) {
        if (bkt[j] >= 0) {
            int p = atomicAdd(&cur[bkt[j]], 1);
            stage[p] = payload[j];
        }
    }
    __syncthreads();

    const int wv = t >> 6;
    const int lane = t & 63;
    for (int b = wv; b < NBUCK; b += 4) {
        int cntb = hist[b];
        if (cntb == 0) continue;
        int lo = lofs[b] - cntb;
        int gb = gbase[b];
        for (int k = lane; k < cntb; k += 64) buck[gb + k] = stage[lo + k];
    }
}

// ---- pass 2: one block per bucket; LDS per-node cursors; write final ssrc ----
__global__ __launch_bounds__(256) void bucket2_kernel(const int* __restrict__ off,
                                                      const int* __restrict__ buck,
                                                      int* __restrict__ ssrc) {
    __shared__ int lcur[BNODES];
    int b = blockIdx.x;
    int base0 = b * BNODES;
    int nn = min(BNODES, N_NODES - base0);
    for (int j = threadIdx.x; j < nn; j += 256) lcur[j] = off[base0 + j];
    __syncthreads();
    int e0 = off[base0];
    int e1 = off[min(base0 + BNODES, N_NODES)];
    for (int i = e0 + threadIdx.x; i < e1; i += 256) {
        int w = buck[i];
        int s = w & 0x1FFFF;
        int dl = w >> 17;
        int pos = atomicAdd(&lcur[dl], 1);
        ssrc[pos] = s;
    }
}

// ================= GEMMs (thread-per-node, W in LDS broadcast); h output fp16 ======

__global__ __launch_bounds__(256) void gemm1_kernel(
    const float* __restrict__ x, const float* __restrict__ W1,
    const float* __restrict__ a_src, const float* __restrict__ a_dst,
    __half* __restrict__ h1, float* __restrict__ als, float* __restrict__ ald) {
    __shared__ float Ws[IN_CH * HID];
    __shared__ float as_s[HID], ad_s[HID];
    for (int v = threadIdx.x; v < IN_CH * HID; v += blockDim.x) Ws[v] = W1[v];
    if (threadIdx.x < HID) { as_s[threadIdx.x] = a_src[threadIdx.x]; ad_s[threadIdx.x] = a_dst[threadIdx.x]; }
    __syncthreads();
    int n = blockIdx.x * blockDim.x + threadIdx.x;
    if (n >= N_NODES) return;

    float acc[HID];
#pragma unroll
    for (int c = 0; c < HID; c++) acc[c] = 0.f;

    const float4* xrow = reinterpret_cast<const float4*>(x + (size_t)n * IN_CH);
#pragma unroll 2
    for (int kq = 0; kq < IN_CH / 4; kq++) {
        float4 xv = xrow[kq];
#pragma unroll
        for (int j = 0; j < 4; j++) {
            float xs = (j == 0) ? xv.x : (j == 1) ? xv.y : (j == 2) ? xv.z : xv.w;
            const float4* wr = reinterpret_cast<const float4*>(&Ws[(kq * 4 + j) * HID]);
#pragma unroll
            for (int cq = 0; cq < HID / 4; cq++) {
                float4 wv = wr[cq];
                acc[cq * 4 + 0] += xs * wv.x;
                acc[cq * 4 + 1] += xs * wv.y;
                acc[cq * 4 + 2] += xs * wv.z;
                acc[cq * 4 + 3] += xs * wv.w;
            }
        }
    }
    float s1 = 0.f, s2 = 0.f;
    __half2* hrow = reinterpret_cast<__half2*>(h1 + (size_t)n * HID);
#pragma unroll
    for (int cq = 0; cq < HID / 2; cq++) {
        hrow[cq] = __floats2half2_rn(acc[cq * 2 + 0], acc[cq * 2 + 1]);
        s1 += acc[cq * 2 + 0] * as_s[cq * 2 + 0] + acc[cq * 2 + 1] * as_s[cq * 2 + 1];
        s2 += acc[cq * 2 + 0] * ad_s[cq * 2 + 0] + acc[cq * 2 + 1] * ad_s[cq * 2 + 1];
    }
    als[n] = s1;
    ald[n] = s2;
}

__global__ __launch_bounds__(256) void gemm2_kernel(
    const float* __restrict__ hin, const float* __restrict__ W2,
    const float* __restrict__ a_src, const float* __restrict__ a_dst,
    __half* __restrict__ h2, float* __restrict__ als, float* __restrict__ ald) {
    __shared__ float Ws[HID * OUTC];
    __shared__ float as_s[OUTC], ad_s[OUTC];
    for (int v = threadIdx.x; v < HID * OUTC; v += blockDim.x) Ws[v] = W2[v];
    if (threadIdx.x < OUTC) { as_s[threadIdx.x] = a_src[threadIdx.x]; ad_s[threadIdx.x] = a_dst[threadIdx.x]; }
    __syncthreads();
    int n = blockIdx.x * blockDim.x + threadIdx.x;
    if (n >= N_NODES) return;

    float acc[OUTC];
#pragma unroll
    for (int c = 0; c < OUTC; c++) acc[c] = 0.f;

    const float4* xrow = reinterpret_cast<const float4*>(hin + (size_t)n * HID);
#pragma unroll 2
    for (int kq = 0; kq < HID / 4; kq++) {
        float4 xv = xrow[kq];
#pragma unroll
        for (int j = 0; j < 4; j++) {
            float xs = (j == 0) ? xv.x : (j == 1) ? xv.y : (j == 2) ? xv.z : xv.w;
            const float4* wr = reinterpret_cast<const float4*>(&Ws[(kq * 4 + j) * OUTC]);
#pragma unroll
            for (int cq = 0; cq < OUTC / 4; cq++) {
                float4 wv = wr[cq];
                acc[cq * 4 + 0] += xs * wv.x;
                acc[cq * 4 + 1] += xs * wv.y;
                acc[cq * 4 + 2] += xs * wv.z;
                acc[cq * 4 + 3] += xs * wv.w;
            }
        }
    }
    float s1 = 0.f, s2 = 0.f;
    __half2* hrow = reinterpret_cast<__half2*>(h2 + (size_t)n * OUTC);
#pragma unroll
    for (int cq = 0; cq < OUTC / 2; cq++) {
        hrow[cq] = __floats2half2_rn(acc[cq * 2 + 0], acc[cq * 2 + 1]);
        s1 += acc[cq * 2 + 0] * as_s[cq * 2 + 0] + acc[cq * 2 + 1] * as_s[cq * 2 + 1];
        s2 += acc[cq * 2 + 0] * ad_s[cq * 2 + 0] + acc[cq * 2 + 1] * ad_s[cq * 2 + 1];
    }
    als[n] = s1;
    ald[n] = s2;
}

// ================= aggregation: wave per dst node, no-max softmax, fp16 gather =====
// e bounded (|e| <~ 12 for unit-scale logits) -> exp(e) safe in f32; identical
// to max-subtracted softmax up to rounding.
template <int C, bool FINAL>
__global__ __launch_bounds__(256) void agg_kernel(
    const int* __restrict__ off, const int* __restrict__ ssrc,
    const float* __restrict__ als, const float* __restrict__ ald,
    const __half* __restrict__ h, const float* __restrict__ bias,
    float* __restrict__ outp) {
    __shared__ int   sS[4][SEG_CAP];
    __shared__ float sW[4][SEG_CAP];
    const int wv = threadIdx.x >> 6;
    const int lane = threadIdx.x & 63;
    const int d = (blockIdx.x * blockDim.x + threadIdx.x) >> 6;
    if (d >= N_NODES) return;
    const int o0 = off[d];
    const int deg = off[d + 1] - o0;
    const float aldd = ald[d];

    // ---- single pass: w = exp(leakyrelu(als[s]+ald[d])), stage (s,w), sum ----
    float sloc = 0.f;
    for (int t = lane; t < deg; t += 64) {
        int s = ssrc[o0 + t];
        float e = als[s] + aldd;
        e = e > 0.f ? e : NEG_SLOPE * e;
        float w = __expf(e);
        if (t < SEG_CAP) { sS[wv][t] = s; sW[wv][t] = w; }
        sloc += w;
    }
#pragma unroll
    for (int o = 32; o; o >>= 1) sloc += __shfl_xor(sloc, o);
    const float inv = 1.0f / (sloc + 1e-16f);

    // ---- phase C: half-wave per edge, half2 per lane, 2 edges in flight ----
    constexpr int CH2 = C / 2;
    const int half = lane >> 5;
    const int hl = lane & 31;
    float ax = 0.f, ay = 0.f;

    auto fetch_sw = [&](int t, int& s, float& w) {
        if (t < SEG_CAP) { s = sS[wv][t]; w = sW[wv][t]; }
        else {
            s = ssrc[o0 + t];
            float e = als[s] + aldd;
            e = e > 0.f ? e : NEG_SLOPE * e;
            w = __expf(e);
        }
    };

    int t = half;
    for (; t <= deg - 3; t += 4) {
        int s0, s1; float w0, w1;
        fetch_sw(t, s0, w0);
        fetch_sw(t + 2, s1, w1);
        if (hl < CH2) {
            const float2 h0 = __half22float2(*reinterpret_cast<const __half2*>(h + (size_t)s0 * C + 2 * hl));
            const float2 h1v = __half22float2(*reinterpret_cast<const __half2*>(h + (size_t)s1 * C + 2 * hl));
            ax += w0 * h0.x + w1 * h1v.x;
            ay += w0 * h0.y + w1 * h1v.y;
        }
    }
    if (t < deg) {
        int s0; float w0;
        fetch_sw(t, s0, w0);
        if (hl < CH2) {
            const float2 h0 = __half22float2(*reinterpret_cast<const __half2*>(h + (size_t)s0 * C + 2 * hl));
            ax += w0 * h0.x;
            ay += w0 * h0.y;
        }
    }
    ax += __shfl_xor(ax, 32);
    ay += __shfl_xor(ay, 32);

    const bool valid = (half == 0) && (hl < CH2);
    if (!FINAL) {
        if (valid) {
            const float2 bb = reinterpret_cast<const float2*>(bias)[hl];
            float2 v;
            v.x = ax * inv + bb.x;
            v.y = ay * inv + bb.y;
            v.x = v.x > 0.f ? v.x : 0.f;
            v.y = v.y > 0.f ? v.y : 0.f;
            *reinterpret_cast<float2*>(outp + (size_t)d * C + 2 * hl) = v;
        }
    } else {
        float vx = 0.f, vy = 0.f, mm = -1e30f;
        if (valid) {
            const float2 bb = reinterpret_cast<const float2*>(bias)[hl];
            vx = ax * inv + bb.x;
            vy = ay * inv + bb.y;
            mm = fmaxf(vx, vy);
        }
#pragma unroll
        for (int o = 32; o; o >>= 1) mm = fmaxf(mm, __shfl_xor(mm, o));
        float ex = valid ? (__expf(vx - mm) + __expf(vy - mm)) : 0.f;
#pragma unroll
        for (int o = 32; o; o >>= 1) ex += __shfl_xor(ex, o);
        if (valid) {
            const float lse = mm + logf(ex);
            float2 v; v.x = vx - lse; v.y = vy - lse;
            *reinterpret_cast<float2*>(outp + (size_t)d * C + 2 * hl) = v;
        }
    }
}

extern "C" void kernel_launch(void* const* d_in, const int* in_sizes, int n_in,
                              void* d_out, int out_size, void* d_ws, size_t ws_size,
                              hipStream_t stream) {
    const float* x   = (const float*)d_in[0];
    const int*   ei  = (const int*)d_in[1];
    const float* W1  = (const float*)d_in[2];
    const float* as1 = (const float*)d_in[3];
    const float* ad1 = (const float*)d_in[4];
    const float* b1  = (const float*)d_in[5];
    const float* W2  = (const float*)d_in[6];
    const float* as2 = (const float*)d_in[7];
    const float* ad2 = (const float*)d_in[8];
    const float* b2  = (const float*)d_in[9];
    float* out = (float*)d_out;

    float* A    = (float*)d_ws;                        // N*64 f32 region: buck -> h1(fp16) -> h2(fp16)
    float* B    = A + (size_t)N_NODES * 64;            // N*64 f32 : layer-1 output / gemm2 input
    float* als  = B + (size_t)N_NODES * 64;            // N
    float* ald  = als + N_NODES;                       // N
    int* cnt    = (int*)(ald + N_NODES);               // N
    int* off    = cnt + N_NODES;                       // N+1
    int* blockSum = off + (N_NODES + 1);               // pad 256
    int* bcur   = blockSum + 256;                      // NBUCK*16
    int* ssrc   = bcur + NBUCK * 16;                   // ETOT
    int* buck   = (int*)A;                             // ETOT, aliases A (pre-gemm1 only)
    __half* h16 = (__half*)A;                          // N*64 fp16, aliases A (post-bucket1)

    const int* srcA = ei;
    const int* dstA = ei + N_EDGESC;

    // ---- build dst-sorted edge structure (shared by both layers) ----
    hipMemsetAsync(cnt, 0, N_NODES * sizeof(int), stream);
    hist_kernel<<<(ETOT + 255) / 256, 256, 0, stream>>>(dstA, cnt);
    scanA_kernel<<<NSCAN_BLOCKS, 256, 0, stream>>>(cnt, off, blockSum);
    scanB_kernel<<<1, 128, 0, stream>>>(blockSum);
    scanC_kernel<<<(N_NODES + 255) / 256, 256, 0, stream>>>(off, blockSum, bcur);
    bucket1_kernel<<<(ETOT + TILE - 1) / TILE, 256, 0, stream>>>(srcA, dstA, bcur, buck);
    bucket2_kernel<<<NBUCK, 256, 0, stream>>>(off, buck, ssrc);

    // ---- layer 1 ----
    gemm1_kernel<<<(N_NODES + 255) / 256, 256, 0, stream>>>(x, W1, as1, ad1, h16, als, ald);
    agg_kernel<HID, false><<<(N_NODES * 64 + 255) / 256, 256, 0, stream>>>(off, ssrc, als, ald, h16, b1, B);

    // ---- layer 2 ----
    gemm2_kernel<<<(N_NODES + 255) / 256, 256, 0, stream>>>(B, W2, as2, ad2, h16, als, ald);
    agg_kernel<OUTC, true><<<(N_NODES * 64 + 255) / 256, 256, 0, stream>>>(off, ssrc, als, ald, h16, b2, out);
}

// Round 8
// 232.113 us; speedup vs baseline: 2.2013x; 1.3836x over previous
//
#include <hip/hip_runtime.h>
#include <hip/hip_fp16.h>

#define N_NODES 100000
#define N_EDGESC 1600000
#define ETOT (N_EDGESC + N_NODES)
#define IN_CH 128
#define HID 64
#define OUTC 40
#define NEG_SLOPE 0.2f
#define SEG_CAP 128
#define BNODES 512                                   // nodes per bucket
#define NBUCK ((N_NODES + BNODES - 1) / BNODES)      // 196
#define BCAP 10240                                   // edge slots per bucket (mean 8704, sd ~93)
#define TILE 8192                                    // edges per bucket1 block
#define EPT (TILE / 256)

// ---- init per-bucket cursors to fixed-capacity bases ----
__global__ void initB_kernel(int* __restrict__ bcur) {
    int b = blockIdx.x * blockDim.x + threadIdx.x;
    if (b < NBUCK) bcur[b * 16] = b * BCAP;
}

// ---- pass 1: block-local LDS binning, one global atomic per (block,bucket) ----
// payload = (d_loc<<17)|src
__global__ __launch_bounds__(256) void bucket1_kernel(const int* __restrict__ src,
                                                      const int* __restrict__ dst,
                                                      int* __restrict__ bcur,
                                                      int* __restrict__ buck) {
    __shared__ int hist[256];
    __shared__ int lofs[256];
    __shared__ int gbase[256];
    __shared__ int cur[256];
    __shared__ int stage[TILE];

    const int t = threadIdx.x;
    const int t0 = blockIdx.x * TILE;
    hist[t] = 0;
    __syncthreads();

    int payload[EPT];
    int bkt[EPT];
#pragma unroll
    for (int j = 0; j < EPT; j++) {
        int i = t0 + j * 256 + t;
        if (i < ETOT) {
            int s, d;
            if (i < N_EDGESC) { s = src[i]; d = dst[i]; } else { s = d = i - N_EDGESC; }
            int b = d / BNODES;
            bkt[j] = b;
            payload[j] = ((d & (BNODES - 1)) << 17) | s;
            atomicAdd(&hist[b], 1);
        } else {
            bkt[j] = -1;
            payload[j] = 0;
        }
    }
    __syncthreads();

    int hv = hist[t];
    lofs[t] = hv;
    __syncthreads();
    for (int o = 1; o < 256; o <<= 1) {
        int v = (t >= o) ? lofs[t - o] : 0;
        __syncthreads();
        lofs[t] += v;
        __syncthreads();
    }
    cur[t] = lofs[t] - hv;
    if (t < NBUCK && hv > 0) gbase[t] = atomicAdd(&bcur[t * 16], hv);
    __syncthreads();

#pragma unroll
    for (int j = 0; j < EPT; j++) {
        if (bkt[j] >= 0) {
            int p = atomicAdd(&cur[bkt[j]], 1);
            stage[p] = payload[j];
        }
    }
    __syncthreads();

    const int wv = t >> 6;
    const int lane = t & 63;
    for (int b = wv; b < NBUCK; b += 4) {
        int cntb = hist[b];
        if (cntb == 0) continue;
        int lo = lofs[b] - cntb;
        int gb = gbase[b];
        for (int k = lane; k < cntb; k += 64) buck[gb + k] = stage[lo + k];
    }
}

// ---- pass 2: one block per bucket; local histogram+scan -> off/deg; LDS-cursor scatter ----
__global__ __launch_bounds__(256) void bucket2_kernel(const int* __restrict__ bcur,
                                                      const int* __restrict__ buck,
                                                      int* __restrict__ ssrc,
                                                      int* __restrict__ off,
                                                      int* __restrict__ deg) {
    __shared__ int h5[BNODES];
    __shared__ int sdata[256];
    __shared__ int lcur[BNODES];
    const int b = blockIdx.x;
    const int t = threadIdx.x;
    const int base0 = b * BNODES;   // first node of bucket
    const int bbase = b * BCAP;     // first edge slot of bucket
    const int cnt_b = bcur[b * 16] - bbase;

    h5[t] = 0; h5[t + 256] = 0;
    __syncthreads();
    for (int i = t; i < cnt_b; i += 256) atomicAdd(&h5[buck[bbase + i] >> 17], 1);
    __syncthreads();

    int c0 = h5[2 * t], c1 = h5[2 * t + 1];
    int s = c0 + c1;
    sdata[t] = s;
    __syncthreads();
    for (int o = 1; o < 256; o <<= 1) {
        int v = (t >= o) ? sdata[t - o] : 0;
        __syncthreads();
        sdata[t] += v;
        __syncthreads();
    }
    int run = sdata[t] - s;
    int e0 = bbase + run, e1 = bbase + run + c0;
    int n0 = base0 + 2 * t, n1 = n0 + 1;
    if (n0 < N_NODES) { off[n0] = e0; deg[n0] = c0; }
    if (n1 < N_NODES) { off[n1] = e1; deg[n1] = c1; }
    lcur[2 * t] = e0; lcur[2 * t + 1] = e1;
    __syncthreads();

    for (int i = t; i < cnt_b; i += 256) {
        int w = buck[bbase + i];
        int pos = atomicAdd(&lcur[w >> 17], 1);
        ssrc[pos] = w & 0x1FFFF;
    }
}

// ================= GEMM1: x(f32) @ W1 -> h1(fp16), attention logits ================

__global__ __launch_bounds__(256) void gemm1_kernel(
    const float* __restrict__ x, const float* __restrict__ W1,
    const float* __restrict__ a_src, const float* __restrict__ a_dst,
    __half* __restrict__ h1, float* __restrict__ als, float* __restrict__ ald) {
    __shared__ float Ws[IN_CH * HID];
    __shared__ float as_s[HID], ad_s[HID];
    for (int v = threadIdx.x; v < IN_CH * HID; v += blockDim.x) Ws[v] = W1[v];
    if (threadIdx.x < HID) { as_s[threadIdx.x] = a_src[threadIdx.x]; ad_s[threadIdx.x] = a_dst[threadIdx.x]; }
    __syncthreads();
    int n = blockIdx.x * blockDim.x + threadIdx.x;
    if (n >= N_NODES) return;

    float acc[HID];
#pragma unroll
    for (int c = 0; c < HID; c++) acc[c] = 0.f;

    const float4* xrow = reinterpret_cast<const float4*>(x + (size_t)n * IN_CH);
#pragma unroll 2
    for (int kq = 0; kq < IN_CH / 4; kq++) {
        float4 xv = xrow[kq];
#pragma unroll
        for (int j = 0; j < 4; j++) {
            float xs = (j == 0) ? xv.x : (j == 1) ? xv.y : (j == 2) ? xv.z : xv.w;
            const float4* wr = reinterpret_cast<const float4*>(&Ws[(kq * 4 + j) * HID]);
#pragma unroll
            for (int cq = 0; cq < HID / 4; cq++) {
                float4 wv = wr[cq];
                acc[cq * 4 + 0] += xs * wv.x;
                acc[cq * 4 + 1] += xs * wv.y;
                acc[cq * 4 + 2] += xs * wv.z;
                acc[cq * 4 + 3] += xs * wv.w;
            }
        }
    }
    float s1 = 0.f, s2 = 0.f;
    __half2* hrow = reinterpret_cast<__half2*>(h1 + (size_t)n * HID);
#pragma unroll
    for (int cq = 0; cq < HID / 2; cq++) {
        hrow[cq] = __floats2half2_rn(acc[cq * 2 + 0], acc[cq * 2 + 1]);
        s1 += acc[cq * 2 + 0] * as_s[cq * 2 + 0] + acc[cq * 2 + 1] * as_s[cq * 2 + 1];
        s2 += acc[cq * 2 + 0] * ad_s[cq * 2 + 0] + acc[cq * 2 + 1] * ad_s[cq * 2 + 1];
    }
    als[n] = s1;
    ald[n] = s2;
}

// ================= GEMM2: h2in(fp16) @ W2 -> h2(fp16), attention logits ============

__global__ __launch_bounds__(256) void gemm2_kernel(
    const __half* __restrict__ hin, const float* __restrict__ W2,
    const float* __restrict__ a_src, const float* __restrict__ a_dst,
    __half* __restrict__ h2, float* __restrict__ als, float* __restrict__ ald) {
    __shared__ float Ws[HID * OUTC];
    __shared__ float as_s[OUTC], ad_s[OUTC];
    for (int v = threadIdx.x; v < HID * OUTC; v += blockDim.x) Ws[v] = W2[v];
    if (threadIdx.x < OUTC) { as_s[threadIdx.x] = a_src[threadIdx.x]; ad_s[threadIdx.x] = a_dst[threadIdx.x]; }
    __syncthreads();
    int n = blockIdx.x * blockDim.x + threadIdx.x;
    if (n >= N_NODES) return;

    float acc[OUTC];
#pragma unroll
    for (int c = 0; c < OUTC; c++) acc[c] = 0.f;

    const uint4* xrow = reinterpret_cast<const uint4*>(hin + (size_t)n * HID);
#pragma unroll
    for (int kq = 0; kq < HID / 8; kq++) {
        union { uint4 u; __half2 h[4]; } uu;
        uu.u = xrow[kq];
        float xs8[8];
#pragma unroll
        for (int j = 0; j < 4; j++) {
            float2 f = __half22float2(uu.h[j]);
            xs8[2 * j] = f.x; xs8[2 * j + 1] = f.y;
        }
#pragma unroll
        for (int jj = 0; jj < 8; jj++) {
            float xs = xs8[jj];
            const float4* wr = reinterpret_cast<const float4*>(&Ws[(kq * 8 + jj) * OUTC]);
#pragma unroll
            for (int cq = 0; cq < OUTC / 4; cq++) {
                float4 wv = wr[cq];
                acc[cq * 4 + 0] += xs * wv.x;
                acc[cq * 4 + 1] += xs * wv.y;
                acc[cq * 4 + 2] += xs * wv.z;
                acc[cq * 4 + 3] += xs * wv.w;
            }
        }
    }
    float s1 = 0.f, s2 = 0.f;
    __half2* hrow = reinterpret_cast<__half2*>(h2 + (size_t)n * OUTC);
#pragma unroll
    for (int cq = 0; cq < OUTC / 2; cq++) {
        hrow[cq] = __floats2half2_rn(acc[cq * 2 + 0], acc[cq * 2 + 1]);
        s1 += acc[cq * 2 + 0] * as_s[cq * 2 + 0] + acc[cq * 2 + 1] * as_s[cq * 2 + 1];
        s2 += acc[cq * 2 + 0] * ad_s[cq * 2 + 0] + acc[cq * 2 + 1] * ad_s[cq * 2 + 1];
    }
    als[n] = s1;
    ald[n] = s2;
}

// ================= aggregation: wave/node; quarter-wave/edge; packed LDS stage =====
// no-max softmax (|e| bounded -> exp safe in f32)
template <int C, bool FINAL, typename OutT>
__global__ __launch_bounds__(256) void agg_kernel(
    const int* __restrict__ off, const int* __restrict__ degs,
    const int* __restrict__ ssrc,
    const float* __restrict__ als, const float* __restrict__ ald,
    const __half* __restrict__ h, const float* __restrict__ bias,
    OutT* __restrict__ outp) {
    __shared__ int2 sSW[4][SEG_CAP];
    const int wv = threadIdx.x >> 6;
    const int lane = threadIdx.x & 63;
    const int d = (blockIdx.x * blockDim.x + threadIdx.x) >> 6;
    if (d >= N_NODES) return;
    const int o0 = off[d];
    const int deg = degs[d];
    const float aldd = ald[d];

    // ---- phase AB: gather als, w=exp(leakyrelu), stage packed (s,w), wave-sum ----
    float sloc = 0.f;
    for (int t = lane; t < deg; t += 64) {
        int s = ssrc[o0 + t];
        float e = als[s] + aldd;
        e = e > 0.f ? e : NEG_SLOPE * e;
        float w = __expf(e);
        if (t < SEG_CAP) sSW[wv][t] = make_int2(s, __float_as_int(w));
        sloc += w;
    }
#pragma unroll
    for (int o = 32; o; o >>= 1) sloc += __shfl_xor(sloc, o);
    const float inv = 1.0f / (sloc + 1e-16f);

    // ---- phase C: quarter-wave per edge, 4ch/lane (8B), 2 edges unrolled ----
    constexpr int QL = C / 4;
    const int q = lane >> 4;
    const int ql = lane & 15;
    const bool lactive = (ql < QL);
    float a0 = 0.f, a1 = 0.f, a2 = 0.f, a3 = 0.f;

    auto body = [&](int s, float w) {
        union { float2 f; __half2 h2[2]; } u;
        u.f = *reinterpret_cast<const float2*>(h + (size_t)s * C + 4 * ql);
        float2 lo = __half22float2(u.h2[0]);
        float2 hi = __half22float2(u.h2[1]);
        a0 += w * lo.x; a1 += w * lo.y; a2 += w * hi.x; a3 += w * hi.y;
    };

    if (deg <= SEG_CAP) {
        int t = q;
        for (; t + 4 < deg; t += 8) {
            int2 p0 = sSW[wv][t];
            int2 p1 = sSW[wv][t + 4];
            if (lactive) {
                body(p0.x, __int_as_float(p0.y));
                body(p1.x, __int_as_float(p1.y));
            }
        }
        if (t < deg) {
            int2 p0 = sSW[wv][t];
            if (lactive) body(p0.x, __int_as_float(p0.y));
        }
    } else {
        for (int t = q; t < deg; t += 4) {
            int s; float w;
            if (t < SEG_CAP) { int2 p = sSW[wv][t]; s = p.x; w = __int_as_float(p.y); }
            else {
                s = ssrc[o0 + t];
                float e = als[s] + aldd;
                e = e > 0.f ? e : NEG_SLOPE * e;
                w = __expf(e);
            }
            if (lactive) body(s, w);
        }
    }

    a0 += __shfl_xor(a0, 16); a0 += __shfl_xor(a0, 32);
    a1 += __shfl_xor(a1, 16); a1 += __shfl_xor(a1, 32);
    a2 += __shfl_xor(a2, 16); a2 += __shfl_xor(a2, 32);
    a3 += __shfl_xor(a3, 16); a3 += __shfl_xor(a3, 32);

    const bool valid = (q == 0) && lactive;
    if (!FINAL) {
        if (valid) {
            const float4 bb = reinterpret_cast<const float4*>(bias)[ql];
            float v0 = fmaxf(a0 * inv + bb.x, 0.f);
            float v1 = fmaxf(a1 * inv + bb.y, 0.f);
            float v2 = fmaxf(a2 * inv + bb.z, 0.f);
            float v3 = fmaxf(a3 * inv + bb.w, 0.f);
            union { __half2 h2[2]; uint2 u; } pk;
            pk.h2[0] = __floats2half2_rn(v0, v1);
            pk.h2[1] = __floats2half2_rn(v2, v3);
            *reinterpret_cast<uint2*>(reinterpret_cast<__half*>(outp) + (size_t)d * C + 4 * ql) = pk.u;
        }
    } else {
        float v0 = 0.f, v1 = 0.f, v2 = 0.f, v3 = 0.f, mm = -1e30f;
        if (valid) {
            const float4 bb = reinterpret_cast<const float4*>(bias)[ql];
            v0 = a0 * inv + bb.x;
            v1 = a1 * inv + bb.y;
            v2 = a2 * inv + bb.z;
            v3 = a3 * inv + bb.w;
            mm = fmaxf(fmaxf(v0, v1), fmaxf(v2, v3));
        }
#pragma unroll
        for (int o = 8; o; o >>= 1) mm = fmaxf(mm, __shfl_xor(mm, o));
        float ex = valid ? (__expf(v0 - mm) + __expf(v1 - mm) + __expf(v2 - mm) + __expf(v3 - mm)) : 0.f;
#pragma unroll
        for (int o = 8; o; o >>= 1) ex += __shfl_xor(ex, o);
        if (valid) {
            float lse = mm + logf(ex);
            float4 vv;
            vv.x = v0 - lse; vv.y = v1 - lse; vv.z = v2 - lse; vv.w = v3 - lse;
            *reinterpret_cast<float4*>(reinterpret_cast<float*>(outp) + (size_t)d * C + 4 * ql) = vv;
        }
    }
}

extern "C" void kernel_launch(void* const* d_in, const int* in_sizes, int n_in,
                              void* d_out, int out_size, void* d_ws, size_t ws_size,
                              hipStream_t stream) {
    const float* x   = (const float*)d_in[0];
    const int*   ei  = (const int*)d_in[1];
    const float* W1  = (const float*)d_in[2];
    const float* as1 = (const float*)d_in[3];
    const float* ad1 = (const float*)d_in[4];
    const float* b1  = (const float*)d_in[5];
    const float* W2  = (const float*)d_in[6];
    const float* as2 = (const float*)d_in[7];
    const float* ad2 = (const float*)d_in[8];
    const float* b2  = (const float*)d_in[9];
    float* out = (float*)d_out;

    char* p = (char*)d_ws;
    auto alloc = [&](size_t bytes) { void* r = p; p += (bytes + 63) & ~(size_t)63; return r; };

    // region0: buck (sort scratch) then h1/h2 fp16 — sequential lifetimes
    size_t r0 = (size_t)N_NODES * 64 * sizeof(__half);            // 12.8 MB >= buck 8.03 MB
    size_t buckBytes = (size_t)NBUCK * BCAP * sizeof(int);
    void* region0 = alloc(r0 > buckBytes ? r0 : buckBytes);
    __half* h16 = (__half*)region0;
    int* buck   = (int*)region0;

    __half* B16 = (__half*)alloc((size_t)N_NODES * 64 * sizeof(__half));  // layer-1 out
    float* als  = (float*)alloc((size_t)N_NODES * sizeof(float));
    float* ald  = (float*)alloc((size_t)N_NODES * sizeof(float));
    int* off    = (int*)alloc((size_t)N_NODES * sizeof(int));
    int* deg    = (int*)alloc((size_t)N_NODES * sizeof(int));
    int* bcur   = (int*)alloc((size_t)NBUCK * 16 * sizeof(int));
    int* ssrc   = (int*)alloc((size_t)NBUCK * BCAP * sizeof(int));

    const int* srcA = ei;
    const int* dstA = ei + N_EDGESC;

    // ---- build dst-sorted edge structure (fixed-capacity buckets, no global scan) ----
    initB_kernel<<<1, 256, 0, stream>>>(bcur);
    bucket1_kernel<<<(ETOT + TILE - 1) / TILE, 256, 0, stream>>>(srcA, dstA, bcur, buck);
    bucket2_kernel<<<NBUCK, 256, 0, stream>>>(bcur, buck, ssrc, off, deg);

    // ---- layer 1 ----
    gemm1_kernel<<<(N_NODES + 255) / 256, 256, 0, stream>>>(x, W1, as1, ad1, h16, als, ald);
    agg_kernel<HID, false, __half><<<(N_NODES * 64 + 255) / 256, 256, 0, stream>>>(
        off, deg, ssrc, als, ald, h16, b1, B16);

    // ---- layer 2 ----
    gemm2_kernel<<<(N_NODES + 255) / 256, 256, 0, stream>>>(B16, W2, as2, ad2, h16, als, ald);
    agg_kernel<OUTC, true, float><<<(N_NODES * 64 + 255) / 256, 256, 0, stream>>>(
        off, deg, ssrc, als, ald, h16, b2, out);
}

// Round 9
// 228.253 us; speedup vs baseline: 2.2385x; 1.0169x over previous
//
#include <hip/hip_runtime.h>
#include <hip/hip_fp16.h>

#define N_NODES 100000
#define N_EDGESC 1600000
#define ETOT (N_EDGESC + N_NODES)
#define IN_CH 128
#define HID 64
#define OUTC 40
#define NEG_SLOPE 0.2f
#define SEG_CAP 128
#define BNODES 512                                   // nodes per bucket
#define NBUCK ((N_NODES + BNODES - 1) / BNODES)      // 196
#define BCAP 10240                                   // edge slots per bucket (mean 8704, sd ~93)
#define TILE 8192                                    // edges per bucket1 block
#define EPT (TILE / 256)

// ---- init per-bucket cursors to fixed-capacity bases ----
__global__ void initB_kernel(int* __restrict__ bcur) {
    int b = blockIdx.x * blockDim.x + threadIdx.x;
    if (b < NBUCK) bcur[b * 16] = b * BCAP;
}

// ---- pass 1: block-local LDS binning, one global atomic per (block,bucket) ----
// payload = (d_loc<<17)|src
__global__ __launch_bounds__(256) void bucket1_kernel(const int* __restrict__ src,
                                                      const int* __restrict__ dst,
                                                      int* __restrict__ bcur,
                                                      int* __restrict__ buck) {
    __shared__ int hist[256];
    __shared__ int lofs[256];
    __shared__ int gbase[256];
    __shared__ int cur[256];
    __shared__ int stage[TILE];

    const int t = threadIdx.x;
    const int t0 = blockIdx.x * TILE;
    hist[t] = 0;
    __syncthreads();

    int payload[EPT];
    int bkt[EPT];
#pragma unroll
    for (int j = 0; j < EPT; j++) {
        int i = t0 + j * 256 + t;
        if (i < ETOT) {
            int s, d;
            if (i < N_EDGESC) { s = src[i]; d = dst[i]; } else { s = d = i - N_EDGESC; }
            int b = d / BNODES;
            bkt[j] = b;
            payload[j] = ((d & (BNODES - 1)) << 17) | s;
            atomicAdd(&hist[b], 1);
        } else {
            bkt[j] = -1;
            payload[j] = 0;
        }
    }
    __syncthreads();

    int hv = hist[t];
    lofs[t] = hv;
    __syncthreads();
    for (int o = 1; o < 256; o <<= 1) {
        int v = (t >= o) ? lofs[t - o] : 0;
        __syncthreads();
        lofs[t] += v;
        __syncthreads();
    }
    cur[t] = lofs[t] - hv;
    if (t < NBUCK && hv > 0) gbase[t] = atomicAdd(&bcur[t * 16], hv);
    __syncthreads();

#pragma unroll
    for (int j = 0; j < EPT; j++) {
        if (bkt[j] >= 0) {
            int p = atomicAdd(&cur[bkt[j]], 1);
            stage[p] = payload[j];
        }
    }
    __syncthreads();

    const int wv = t >> 6;
    const int lane = t & 63;
    for (int b = wv; b < NBUCK; b += 4) {
        int cntb = hist[b];
        if (cntb == 0) continue;
        int lo = lofs[b] - cntb;
        int gb = gbase[b];
        for (int k = lane; k < cntb; k += 64) buck[gb + k] = stage[lo + k];
    }
}

// ---- pass 2: one block per bucket; local histogram+scan -> off/deg; LDS-cursor scatter ----
__global__ __launch_bounds__(256) void bucket2_kernel(const int* __restrict__ bcur,
                                                      const int* __restrict__ buck,
                                                      int* __restrict__ ssrc,
                                                      int* __restrict__ off,
                                                      int* __restrict__ deg) {
    __shared__ int h5[BNODES];
    __shared__ int sdata[256];
    __shared__ int lcur[BNODES];
    const int b = blockIdx.x;
    const int t = threadIdx.x;
    const int base0 = b * BNODES;
    const int bbase = b * BCAP;
    const int cnt_b = bcur[b * 16] - bbase;

    h5[t] = 0; h5[t + 256] = 0;
    __syncthreads();
    for (int i = t; i < cnt_b; i += 256) atomicAdd(&h5[buck[bbase + i] >> 17], 1);
    __syncthreads();

    int c0 = h5[2 * t], c1 = h5[2 * t + 1];
    int s = c0 + c1;
    sdata[t] = s;
    __syncthreads();
    for (int o = 1; o < 256; o <<= 1) {
        int v = (t >= o) ? sdata[t - o] : 0;
        __syncthreads();
        sdata[t] += v;
        __syncthreads();
    }
    int run = sdata[t] - s;
    int e0 = bbase + run, e1 = bbase + run + c0;
    int n0 = base0 + 2 * t, n1 = n0 + 1;
    if (n0 < N_NODES) { off[n0] = e0; deg[n0] = c0; }
    if (n1 < N_NODES) { off[n1] = e1; deg[n1] = c1; }
    lcur[2 * t] = e0; lcur[2 * t + 1] = e1;
    __syncthreads();

    for (int i = t; i < cnt_b; i += 256) {
        int w = buck[bbase + i];
        int pos = atomicAdd(&lcur[w >> 17], 1);
        ssrc[pos] = w & 0x1FFFF;
    }
}

// ================= GEMM1: x(f32) @ W1 -> h1(fp16), attention logits ================

__global__ __launch_bounds__(256) void gemm1_kernel(
    const float* __restrict__ x, const float* __restrict__ W1,
    const float* __restrict__ a_src, const float* __restrict__ a_dst,
    __half* __restrict__ h1, float* __restrict__ als, float* __restrict__ ald) {
    __shared__ float Ws[IN_CH * HID];
    __shared__ float as_s[HID], ad_s[HID];
    for (int v = threadIdx.x; v < IN_CH * HID; v += blockDim.x) Ws[v] = W1[v];
    if (threadIdx.x < HID) { as_s[threadIdx.x] = a_src[threadIdx.x]; ad_s[threadIdx.x] = a_dst[threadIdx.x]; }
    __syncthreads();
    int n = blockIdx.x * blockDim.x + threadIdx.x;
    if (n >= N_NODES) return;

    float acc[HID];
#pragma unroll
    for (int c = 0; c < HID; c++) acc[c] = 0.f;

    const float4* xrow = reinterpret_cast<const float4*>(x + (size_t)n * IN_CH);
#pragma unroll 2
    for (int kq = 0; kq < IN_CH / 4; kq++) {
        float4 xv = xrow[kq];
#pragma unroll
        for (int j = 0; j < 4; j++) {
            float xs = (j == 0) ? xv.x : (j == 1) ? xv.y : (j == 2) ? xv.z : xv.w;
            const float4* wr = reinterpret_cast<const float4*>(&Ws[(kq * 4 + j) * HID]);
#pragma unroll
            for (int cq = 0; cq < HID / 4; cq++) {
                float4 wv = wr[cq];
                acc[cq * 4 + 0] += xs * wv.x;
                acc[cq * 4 + 1] += xs * wv.y;
                acc[cq * 4 + 2] += xs * wv.z;
                acc[cq * 4 + 3] += xs * wv.w;
            }
        }
    }
    float s1 = 0.f, s2 = 0.f;
    __half2* hrow = reinterpret_cast<__half2*>(h1 + (size_t)n * HID);
#pragma unroll
    for (int cq = 0; cq < HID / 2; cq++) {
        hrow[cq] = __floats2half2_rn(acc[cq * 2 + 0], acc[cq * 2 + 1]);
        s1 += acc[cq * 2 + 0] * as_s[cq * 2 + 0] + acc[cq * 2 + 1] * as_s[cq * 2 + 1];
        s2 += acc[cq * 2 + 0] * ad_s[cq * 2 + 0] + acc[cq * 2 + 1] * ad_s[cq * 2 + 1];
    }
    als[n] = s1;
    ald[n] = s2;
}

// ================= GEMM2: h2in(fp16) @ W2 -> h2(fp16), attention logits ============

__global__ __launch_bounds__(256) void gemm2_kernel(
    const __half* __restrict__ hin, const float* __restrict__ W2,
    const float* __restrict__ a_src, const float* __restrict__ a_dst,
    __half* __restrict__ h2, float* __restrict__ als, float* __restrict__ ald) {
    __shared__ float Ws[HID * OUTC];
    __shared__ float as_s[OUTC], ad_s[OUTC];
    for (int v = threadIdx.x; v < HID * OUTC; v += blockDim.x) Ws[v] = W2[v];
    if (threadIdx.x < OUTC) { as_s[threadIdx.x] = a_src[threadIdx.x]; ad_s[threadIdx.x] = a_dst[threadIdx.x]; }
    __syncthreads();
    int n = blockIdx.x * blockDim.x + threadIdx.x;
    if (n >= N_NODES) return;

    float acc[OUTC];
#pragma unroll
    for (int c = 0; c < OUTC; c++) acc[c] = 0.f;

    const uint4* xrow = reinterpret_cast<const uint4*>(hin + (size_t)n * HID);
#pragma unroll
    for (int kq = 0; kq < HID / 8; kq++) {
        union { uint4 u; __half2 h[4]; } uu;
        uu.u = xrow[kq];
        float xs8[8];
#pragma unroll
        for (int j = 0; j < 4; j++) {
            float2 f = __half22float2(uu.h[j]);
            xs8[2 * j] = f.x; xs8[2 * j + 1] = f.y;
        }
#pragma unroll
        for (int jj = 0; jj < 8; jj++) {
            float xs = xs8[jj];
            const float4* wr = reinterpret_cast<const float4*>(&Ws[(kq * 8 + jj) * OUTC]);
#pragma unroll
            for (int cq = 0; cq < OUTC / 4; cq++) {
                float4 wv = wr[cq];
                acc[cq * 4 + 0] += xs * wv.x;
                acc[cq * 4 + 1] += xs * wv.y;
                acc[cq * 4 + 2] += xs * wv.z;
                acc[cq * 4 + 3] += xs * wv.w;
            }
        }
    }
    float s1 = 0.f, s2 = 0.f;
    __half2* hrow = reinterpret_cast<__half2*>(h2 + (size_t)n * OUTC);
#pragma unroll
    for (int cq = 0; cq < OUTC / 2; cq++) {
        hrow[cq] = __floats2half2_rn(acc[cq * 2 + 0], acc[cq * 2 + 1]);
        s1 += acc[cq * 2 + 0] * as_s[cq * 2 + 0] + acc[cq * 2 + 1] * as_s[cq * 2 + 1];
        s2 += acc[cq * 2 + 0] * ad_s[cq * 2 + 0] + acc[cq * 2 + 1] * ad_s[cq * 2 + 1];
    }
    als[n] = s1;
    ald[n] = s2;
}

// ================= aggregation v3: wave/node; 8 lanes/edge; normalized fp16 wn; hfma2 ====
// no-max softmax (|e| bounded -> exp safe in f32); wn = w/sum in [0,1] -> fp16-safe accum.
__device__ __forceinline__ __half2 shfl_xor_h2(__half2 v, int o) {
    int i = *reinterpret_cast<int*>(&v);
    i = __shfl_xor(i, o);
    return *reinterpret_cast<__half2*>(&i);
}

template <int C, bool FINAL, typename OutT>
__global__ __launch_bounds__(256) void agg_kernel(
    const int* __restrict__ off, const int* __restrict__ degs,
    const int* __restrict__ ssrc,
    const float* __restrict__ als, const float* __restrict__ ald,
    const __half* __restrict__ h, const float* __restrict__ bias,
    OutT* __restrict__ outp) {
    __shared__ int2 sSW[4][SEG_CAP];
    const int wv = threadIdx.x >> 6;
    const int lane = threadIdx.x & 63;
    const int d = (blockIdx.x * blockDim.x + threadIdx.x) >> 6;
    if (d >= N_NODES) return;
    const int o0 = off[d];
    const int deg = degs[d];
    const float aldd = ald[d];

    // ---- phase AB: gather als, w=exp(leakyrelu), stage (s,w), wave-sum ----
    float sloc = 0.f;
    for (int t = lane; t < deg; t += 64) {
        int s = ssrc[o0 + t];
        float e = als[s] + aldd;
        e = e > 0.f ? e : NEG_SLOPE * e;
        float w = __expf(e);
        if (t < SEG_CAP) sSW[wv][t] = make_int2(s, __float_as_int(w));
        sloc += w;
    }
#pragma unroll
    for (int o = 32; o; o >>= 1) sloc += __shfl_xor(sloc, o);
    const float inv = 1.0f / (sloc + 1e-16f);

    // ---- normalize staged weights to packed half2 (wn, wn) ----
    for (int t = lane; t < deg && t < SEG_CAP; t += 64) {
        int2 p = sSW[wv][t];
        __half2 wn2 = __float2half2_rn(__int_as_float(p.y) * inv);
        p.y = *reinterpret_cast<int*>(&wn2);
        sSW[wv][t] = p;
    }

    // ---- phase C: 8 lanes/edge, 8 ch/lane (16B), hfma2 accumulate, 2x unroll ----
    constexpr int GL = (C + 7) / 8;          // active lanes per 8-lane group
    const int g = lane >> 3;                 // edge slot 0..7
    const int gl = lane & 7;                 // channel octet
    const bool lactive = (gl < GL);
    __half2 a0 = __float2half2_rn(0.f), a1 = a0, a2 = a0, a3 = a0;

    auto body = [&](int s, int wbits) {
        __half2 wn2 = *reinterpret_cast<__half2*>(&wbits);
        union { uint4 u; __half2 h2[4]; } uu;
        uu.u = *reinterpret_cast<const uint4*>(h + (size_t)s * C + 8 * gl);
        a0 = __hfma2(uu.h2[0], wn2, a0);
        a1 = __hfma2(uu.h2[1], wn2, a1);
        a2 = __hfma2(uu.h2[2], wn2, a2);
        a3 = __hfma2(uu.h2[3], wn2, a3);
    };
    auto fetch = [&](int t, int& s, int& wbits) {
        if (t < SEG_CAP) { int2 p = sSW[wv][t]; s = p.x; wbits = p.y; }
        else {
            s = ssrc[o0 + t];
            float e = als[s] + aldd;
            e = e > 0.f ? e : NEG_SLOPE * e;
            __half2 wn2 = __float2half2_rn(__expf(e) * inv);
            wbits = *reinterpret_cast<int*>(&wn2);
        }
    };

    int t = g;
    for (; t + 8 < deg; t += 16) {
        int s0, w0, s1, w1;
        fetch(t, s0, w0);
        fetch(t + 8, s1, w1);
        if (lactive) { body(s0, w0); body(s1, w1); }
    }
    if (t < deg) {
        int s0, w0;
        fetch(t, s0, w0);
        if (lactive) body(s0, w0);
    }

    // reduce across the 8 edge-slots (xor 8,16,32)
#pragma unroll
    for (int o = 8; o <= 32; o <<= 1) {
        a0 = __hadd2(a0, shfl_xor_h2(a0, o));
        a1 = __hadd2(a1, shfl_xor_h2(a1, o));
        a2 = __hadd2(a2, shfl_xor_h2(a2, o));
        a3 = __hadd2(a3, shfl_xor_h2(a3, o));
    }

    const bool valid = (g == 0) && lactive;
    float2 f0 = __half22float2(a0), f1 = __half22float2(a1);
    float2 f2 = __half22float2(a2), f3 = __half22float2(a3);

    if (!FINAL) {
        if (valid) {
            const float4 b0 = reinterpret_cast<const float4*>(bias)[2 * gl];
            const float4 b1 = reinterpret_cast<const float4*>(bias)[2 * gl + 1];
            float v0 = fmaxf(f0.x + b0.x, 0.f), v1 = fmaxf(f0.y + b0.y, 0.f);
            float v2 = fmaxf(f1.x + b0.z, 0.f), v3 = fmaxf(f1.y + b0.w, 0.f);
            float v4 = fmaxf(f2.x + b1.x, 0.f), v5 = fmaxf(f2.y + b1.y, 0.f);
            float v6 = fmaxf(f3.x + b1.z, 0.f), v7 = fmaxf(f3.y + b1.w, 0.f);
            union { __half2 h2[4]; uint4 u; } pk;
            pk.h2[0] = __floats2half2_rn(v0, v1);
            pk.h2[1] = __floats2half2_rn(v2, v3);
            pk.h2[2] = __floats2half2_rn(v4, v5);
            pk.h2[3] = __floats2half2_rn(v6, v7);
            *reinterpret_cast<uint4*>(reinterpret_cast<__half*>(outp) + (size_t)d * C + 8 * gl) = pk.u;
        }
    } else {
        float v[8];
        float mm = -1e30f;
        if (valid) {
            const float4 b0 = reinterpret_cast<const float4*>(bias)[2 * gl];
            const float4 b1 = reinterpret_cast<const float4*>(bias)[2 * gl + 1];
            v[0] = f0.x + b0.x; v[1] = f0.y + b0.y; v[2] = f1.x + b0.z; v[3] = f1.y + b0.w;
            v[4] = f2.x + b1.x; v[5] = f2.y + b1.y; v[6] = f3.x + b1.z; v[7] = f3.y + b1.w;
#pragma unroll
            for (int j = 0; j < 8; j++) mm = fmaxf(mm, v[j]);
        }
#pragma unroll
        for (int o = 1; o <= 4; o <<= 1) mm = fmaxf(mm, __shfl_xor(mm, o));
        float ex = 0.f;
        if (valid) {
#pragma unroll
            for (int j = 0; j < 8; j++) ex += __expf(v[j] - mm);
        }
#pragma unroll
        for (int o = 1; o <= 4; o <<= 1) ex += __shfl_xor(ex, o);
        if (valid) {
            float lse = mm + logf(ex);
            float4 o0v, o1v;
            o0v.x = v[0] - lse; o0v.y = v[1] - lse; o0v.z = v[2] - lse; o0v.w = v[3] - lse;
            o1v.x = v[4] - lse; o1v.y = v[5] - lse; o1v.z = v[6] - lse; o1v.w = v[7] - lse;
            float* orow = reinterpret_cast<float*>(outp) + (size_t)d * C + 8 * gl;
            *reinterpret_cast<float4*>(orow) = o0v;
            *reinterpret_cast<float4*>(orow + 4) = o1v;
        }
    }
}

extern "C" void kernel_launch(void* const* d_in, const int* in_sizes, int n_in,
                              void* d_out, int out_size, void* d_ws, size_t ws_size,
                              hipStream_t stream) {
    const float* x   = (const float*)d_in[0];
    const int*   ei  = (const int*)d_in[1];
    const float* W1  = (const float*)d_in[2];
    const float* as1 = (const float*)d_in[3];
    const float* ad1 = (const float*)d_in[4];
    const float* b1  = (const float*)d_in[5];
    const float* W2  = (const float*)d_in[6];
    const float* as2 = (const float*)d_in[7];
    const float* ad2 = (const float*)d_in[8];
    const float* b2  = (const float*)d_in[9];
    float* out = (float*)d_out;

    char* p = (char*)d_ws;
    auto alloc = [&](size_t bytes) { void* r = p; p += (bytes + 63) & ~(size_t)63; return r; };

    size_t r0 = (size_t)N_NODES * 64 * sizeof(__half);
    size_t buckBytes = (size_t)NBUCK * BCAP * sizeof(int);
    void* region0 = alloc(r0 > buckBytes ? r0 : buckBytes);
    __half* h16 = (__half*)region0;
    int* buck   = (int*)region0;

    __half* B16 = (__half*)alloc((size_t)N_NODES * 64 * sizeof(__half));
    float* als  = (float*)alloc((size_t)N_NODES * sizeof(float));
    float* ald  = (float*)alloc((size_t)N_NODES * sizeof(float));
    int* off    = (int*)alloc((size_t)N_NODES * sizeof(int));
    int* deg    = (int*)alloc((size_t)N_NODES * sizeof(int));
    int* bcur   = (int*)alloc((size_t)NBUCK * 16 * sizeof(int));
    int* ssrc   = (int*)alloc((size_t)NBUCK * BCAP * sizeof(int));

    const int* srcA = ei;
    const int* dstA = ei + N_EDGESC;

    initB_kernel<<<1, 256, 0, stream>>>(bcur);
    bucket1_kernel<<<(ETOT + TILE - 1) / TILE, 256, 0, stream>>>(srcA, dstA, bcur, buck);
    bucket2_kernel<<<NBUCK, 256, 0, stream>>>(bcur, buck, ssrc, off, deg);

    gemm1_kernel<<<(N_NODES + 255) / 256, 256, 0, stream>>>(x, W1, as1, ad1, h16, als, ald);
    agg_kernel<HID, false, __half><<<(N_NODES * 64 + 255) / 256, 256, 0, stream>>>(
        off, deg, ssrc, als, ald, h16, b1, B16);

    gemm2_kernel<<<(N_NODES + 255) / 256, 256, 0, stream>>>(B16, W2, as2, ad2, h16, als, ald);
    agg_kernel<OUTC, true, float><<<(N_NODES * 64 + 255) / 256, 256, 0, stream>>>(
        off, deg, ssrc, als, ald, h16, b2, out);
}

// Round 10
// 220.080 us; speedup vs baseline: 2.3216x; 1.0371x over previous
//
#include <hip/hip_runtime.h>
#include <hip/hip_fp16.h>

#define N_NODES 100000
#define N_EDGESC 1600000
#define ETOT (N_EDGESC + N_NODES)
#define IN_CH 128
#define HID 64
#define OUTC 40
#define NEG_SLOPE 0.2f
#define SEG_CAP 128
#define BNODES 512                                   // nodes per bucket
#define NBUCK ((N_NODES + BNODES - 1) / BNODES)      // 196
#define BCAP 10240                                   // edge slots per bucket (mean 8704, sd ~93)
#define TILE 8192                                    // edges per bucket1 block
#define EPT (TILE / 256)

// ---- init per-bucket cursors to fixed-capacity bases ----
__global__ void initB_kernel(int* __restrict__ bcur) {
    int b = blockIdx.x * blockDim.x + threadIdx.x;
    if (b < NBUCK) bcur[b * 16] = b * BCAP;
}

// ---- pass 1: block-local LDS binning, one global atomic per (block,bucket) ----
__global__ __launch_bounds__(256) void bucket1_kernel(const int* __restrict__ src,
                                                      const int* __restrict__ dst,
                                                      int* __restrict__ bcur,
                                                      int* __restrict__ buck) {
    __shared__ int hist[256];
    __shared__ int lofs[256];
    __shared__ int gbase[256];
    __shared__ int cur[256];
    __shared__ int stage[TILE];

    const int t = threadIdx.x;
    const int t0 = blockIdx.x * TILE;
    hist[t] = 0;
    __syncthreads();

    int payload[EPT];
    int bkt[EPT];
#pragma unroll
    for (int j = 0; j < EPT; j++) {
        int i = t0 + j * 256 + t;
        if (i < ETOT) {
            int s, d;
            if (i < N_EDGESC) { s = src[i]; d = dst[i]; } else { s = d = i - N_EDGESC; }
            int b = d / BNODES;
            bkt[j] = b;
            payload[j] = ((d & (BNODES - 1)) << 17) | s;
            atomicAdd(&hist[b], 1);
        } else {
            bkt[j] = -1;
            payload[j] = 0;
        }
    }
    __syncthreads();

    int hv = hist[t];
    lofs[t] = hv;
    __syncthreads();
    for (int o = 1; o < 256; o <<= 1) {
        int v = (t >= o) ? lofs[t - o] : 0;
        __syncthreads();
        lofs[t] += v;
        __syncthreads();
    }
    cur[t] = lofs[t] - hv;
    if (t < NBUCK && hv > 0) gbase[t] = atomicAdd(&bcur[t * 16], hv);
    __syncthreads();

#pragma unroll
    for (int j = 0; j < EPT; j++) {
        if (bkt[j] >= 0) {
            int p = atomicAdd(&cur[bkt[j]], 1);
            stage[p] = payload[j];
        }
    }
    __syncthreads();

    const int wv = t >> 6;
    const int lane = t & 63;
    for (int b = wv; b < NBUCK; b += 4) {
        int cntb = hist[b];
        if (cntb == 0) continue;
        int lo = lofs[b] - cntb;
        int gb = gbase[b];
        for (int k = lane; k < cntb; k += 64) buck[gb + k] = stage[lo + k];
    }
}

// ---- pass 2: one block per bucket; local histogram+scan -> off/deg; LDS-cursor scatter ----
__global__ __launch_bounds__(256) void bucket2_kernel(const int* __restrict__ bcur,
                                                      const int* __restrict__ buck,
                                                      int* __restrict__ ssrc,
                                                      int* __restrict__ off,
                                                      int* __restrict__ deg) {
    __shared__ int h5[BNODES];
    __shared__ int sdata[256];
    __shared__ int lcur[BNODES];
    const int b = blockIdx.x;
    const int t = threadIdx.x;
    const int base0 = b * BNODES;
    const int bbase = b * BCAP;
    const int cnt_b = bcur[b * 16] - bbase;

    h5[t] = 0; h5[t + 256] = 0;
    __syncthreads();
    for (int i = t; i < cnt_b; i += 256) atomicAdd(&h5[buck[bbase + i] >> 17], 1);
    __syncthreads();

    int c0 = h5[2 * t], c1 = h5[2 * t + 1];
    int s = c0 + c1;
    sdata[t] = s;
    __syncthreads();
    for (int o = 1; o < 256; o <<= 1) {
        int v = (t >= o) ? sdata[t - o] : 0;
        __syncthreads();
        sdata[t] += v;
        __syncthreads();
    }
    int run = sdata[t] - s;
    int e0 = bbase + run, e1 = bbase + run + c0;
    int n0 = base0 + 2 * t, n1 = n0 + 1;
    if (n0 < N_NODES) { off[n0] = e0; deg[n0] = c0; }
    if (n1 < N_NODES) { off[n1] = e1; deg[n1] = c1; }
    lcur[2 * t] = e0; lcur[2 * t + 1] = e1;
    __syncthreads();

    for (int i = t; i < cnt_b; i += 256) {
        int w = buck[bbase + i];
        int pos = atomicAdd(&lcur[w >> 17], 1);
        ssrc[pos] = w & 0x1FFFF;
    }
}

// ================= GEMM1 v2: 4 threads/node, 16 interleaved ch each =================
// chunk c owns channels 16*j + 4*c + i (j=0..3, i=0..3) -> conflict-free LDS float4 reads.
__global__ __launch_bounds__(256) void gemm1_kernel(
    const float* __restrict__ x, const float* __restrict__ W1,
    const float* __restrict__ a_src, const float* __restrict__ a_dst,
    __half* __restrict__ h1, float* __restrict__ als, float* __restrict__ ald) {
    __shared__ float Ws[IN_CH * HID];
    __shared__ float as_s[HID], ad_s[HID];
    for (int v = threadIdx.x; v < IN_CH * HID; v += 256) Ws[v] = W1[v];
    if (threadIdx.x < HID) { as_s[threadIdx.x] = a_src[threadIdx.x]; ad_s[threadIdx.x] = a_dst[threadIdx.x]; }
    __syncthreads();
    const int t = threadIdx.x;
    const int n = blockIdx.x * 64 + (t >> 2);
    const int c = t & 3;
    if (n >= N_NODES) return;

    float acc[16];
#pragma unroll
    for (int i = 0; i < 16; i++) acc[i] = 0.f;

    const float4* xrow = reinterpret_cast<const float4*>(x + (size_t)n * IN_CH);
#pragma unroll 4
    for (int kq = 0; kq < IN_CH / 4; kq++) {
        float4 xv = xrow[kq];
#pragma unroll
        for (int jj = 0; jj < 4; jj++) {
            float xs = (jj == 0) ? xv.x : (jj == 1) ? xv.y : (jj == 2) ? xv.z : xv.w;
            const float4* wr = reinterpret_cast<const float4*>(&Ws[(kq * 4 + jj) * HID + c * 4]);
#pragma unroll
            for (int j = 0; j < 4; j++) {
                float4 wv = wr[j * 4];           // j*16 floats ahead
                acc[j * 4 + 0] += xs * wv.x;
                acc[j * 4 + 1] += xs * wv.y;
                acc[j * 4 + 2] += xs * wv.z;
                acc[j * 4 + 3] += xs * wv.w;
            }
        }
    }

    float s1 = 0.f, s2 = 0.f;
#pragma unroll
    for (int j = 0; j < 4; j++) {
        int cb = j * 16 + c * 4;
#pragma unroll
        for (int i = 0; i < 4; i++) {
            s1 += acc[j * 4 + i] * as_s[cb + i];
            s2 += acc[j * 4 + i] * ad_s[cb + i];
        }
        union { __half2 h2[2]; uint2 u; } pk;
        pk.h2[0] = __floats2half2_rn(acc[j * 4 + 0], acc[j * 4 + 1]);
        pk.h2[1] = __floats2half2_rn(acc[j * 4 + 2], acc[j * 4 + 3]);
        *reinterpret_cast<uint2*>(h1 + (size_t)n * HID + cb) = pk.u;
    }
    s1 += __shfl_xor(s1, 1); s1 += __shfl_xor(s1, 2);
    s2 += __shfl_xor(s2, 1); s2 += __shfl_xor(s2, 2);
    if (c == 0) { als[n] = s1; ald[n] = s2; }
}

// ================= GEMM2 v2: 4 threads/node, 10 interleaved ch each =================
// chunk c owns channels 8*j + 2*c + i (j=0..4, i=0..1) -> conflict-free LDS float2 reads.
__global__ __launch_bounds__(256) void gemm2_kernel(
    const __half* __restrict__ hin, const float* __restrict__ W2,
    const float* __restrict__ a_src, const float* __restrict__ a_dst,
    __half* __restrict__ h2, float* __restrict__ als, float* __restrict__ ald) {
    __shared__ float Ws[HID * OUTC];
    __shared__ float as_s[OUTC], ad_s[OUTC];
    for (int v = threadIdx.x; v < HID * OUTC; v += 256) Ws[v] = W2[v];
    if (threadIdx.x < OUTC) { as_s[threadIdx.x] = a_src[threadIdx.x]; ad_s[threadIdx.x] = a_dst[threadIdx.x]; }
    __syncthreads();
    const int t = threadIdx.x;
    const int n = blockIdx.x * 64 + (t >> 2);
    const int c = t & 3;
    if (n >= N_NODES) return;

    float acc[10];
#pragma unroll
    for (int i = 0; i < 10; i++) acc[i] = 0.f;

    const uint4* xrow = reinterpret_cast<const uint4*>(hin + (size_t)n * HID);
#pragma unroll
    for (int kq = 0; kq < HID / 8; kq++) {
        union { uint4 u; __half2 h[4]; } uu;
        uu.u = xrow[kq];
        float xs8[8];
#pragma unroll
        for (int j = 0; j < 4; j++) {
            float2 f = __half22float2(uu.h[j]);
            xs8[2 * j] = f.x; xs8[2 * j + 1] = f.y;
        }
#pragma unroll
        for (int jj = 0; jj < 8; jj++) {
            float xs = xs8[jj];
            const float2* wr = reinterpret_cast<const float2*>(&Ws[(kq * 8 + jj) * OUTC + c * 2]);
#pragma unroll
            for (int j = 0; j < 5; j++) {
                float2 wv = wr[j * 4];           // j*8 floats ahead
                acc[j * 2 + 0] += xs * wv.x;
                acc[j * 2 + 1] += xs * wv.y;
            }
        }
    }

    float s1 = 0.f, s2 = 0.f;
#pragma unroll
    for (int j = 0; j < 5; j++) {
        int cb = j * 8 + c * 2;
        s1 += acc[j * 2 + 0] * as_s[cb] + acc[j * 2 + 1] * as_s[cb + 1];
        s2 += acc[j * 2 + 0] * ad_s[cb] + acc[j * 2 + 1] * ad_s[cb + 1];
        __half2 pk = __floats2half2_rn(acc[j * 2 + 0], acc[j * 2 + 1]);
        *reinterpret_cast<unsigned*>(h2 + (size_t)n * OUTC + cb) = *reinterpret_cast<unsigned*>(&pk);
    }
    s1 += __shfl_xor(s1, 1); s1 += __shfl_xor(s1, 2);
    s2 += __shfl_xor(s2, 1); s2 += __shfl_xor(s2, 2);
    if (c == 0) { als[n] = s1; ald[n] = s2; }
}

// ================= aggregation v3: wave/node; 8 lanes/edge; normalized fp16 wn; hfma2 ====
__device__ __forceinline__ __half2 shfl_xor_h2(__half2 v, int o) {
    int i = *reinterpret_cast<int*>(&v);
    i = __shfl_xor(i, o);
    return *reinterpret_cast<__half2*>(&i);
}

template <int C, bool FINAL, typename OutT>
__global__ __launch_bounds__(256) void agg_kernel(
    const int* __restrict__ off, const int* __restrict__ degs,
    const int* __restrict__ ssrc,
    const float* __restrict__ als, const float* __restrict__ ald,
    const __half* __restrict__ h, const float* __restrict__ bias,
    OutT* __restrict__ outp) {
    __shared__ int2 sSW[4][SEG_CAP];
    const int wv = threadIdx.x >> 6;
    const int lane = threadIdx.x & 63;
    const int d = (blockIdx.x * blockDim.x + threadIdx.x) >> 6;
    if (d >= N_NODES) return;
    const int o0 = off[d];
    const int deg = degs[d];
    const float aldd = ald[d];

    float sloc = 0.f;
    for (int t = lane; t < deg; t += 64) {
        int s = ssrc[o0 + t];
        float e = als[s] + aldd;
        e = e > 0.f ? e : NEG_SLOPE * e;
        float w = __expf(e);
        if (t < SEG_CAP) sSW[wv][t] = make_int2(s, __float_as_int(w));
        sloc += w;
    }
#pragma unroll
    for (int o = 32; o; o >>= 1) sloc += __shfl_xor(sloc, o);
    const float inv = 1.0f / (sloc + 1e-16f);

    for (int t = lane; t < deg && t < SEG_CAP; t += 64) {
        int2 p = sSW[wv][t];
        __half2 wn2 = __float2half2_rn(__int_as_float(p.y) * inv);
        p.y = *reinterpret_cast<int*>(&wn2);
        sSW[wv][t] = p;
    }

    constexpr int GL = (C + 7) / 8;
    const int g = lane >> 3;
    const int gl = lane & 7;
    const bool lactive = (gl < GL);
    __half2 a0 = __float2half2_rn(0.f), a1 = a0, a2 = a0, a3 = a0;

    auto body = [&](int s, int wbits) {
        __half2 wn2 = *reinterpret_cast<__half2*>(&wbits);
        union { uint4 u; __half2 h2[4]; } uu;
        uu.u = *reinterpret_cast<const uint4*>(h + (size_t)s * C + 8 * gl);
        a0 = __hfma2(uu.h2[0], wn2, a0);
        a1 = __hfma2(uu.h2[1], wn2, a1);
        a2 = __hfma2(uu.h2[2], wn2, a2);
        a3 = __hfma2(uu.h2[3], wn2, a3);
    };
    auto fetch = [&](int t, int& s, int& wbits) {
        if (t < SEG_CAP) { int2 p = sSW[wv][t]; s = p.x; wbits = p.y; }
        else {
            s = ssrc[o0 + t];
            float e = als[s] + aldd;
            e = e > 0.f ? e : NEG_SLOPE * e;
            __half2 wn2 = __float2half2_rn(__expf(e) * inv);
            wbits = *reinterpret_cast<int*>(&wn2);
        }
    };

    int t = g;
    for (; t + 8 < deg; t += 16) {
        int s0, w0, s1, w1;
        fetch(t, s0, w0);
        fetch(t + 8, s1, w1);
        if (lactive) { body(s0, w0); body(s1, w1); }
    }
    if (t < deg) {
        int s0, w0;
        fetch(t, s0, w0);
        if (lactive) body(s0, w0);
    }

#pragma unroll
    for (int o = 8; o <= 32; o <<= 1) {
        a0 = __hadd2(a0, shfl_xor_h2(a0, o));
        a1 = __hadd2(a1, shfl_xor_h2(a1, o));
        a2 = __hadd2(a2, shfl_xor_h2(a2, o));
        a3 = __hadd2(a3, shfl_xor_h2(a3, o));
    }

    const bool valid = (g == 0) && lactive;
    float2 f0 = __half22float2(a0), f1 = __half22float2(a1);
    float2 f2 = __half22float2(a2), f3 = __half22float2(a3);

    if (!FINAL) {
        if (valid) {
            const float4 b0 = reinterpret_cast<const float4*>(bias)[2 * gl];
            const float4 b1 = reinterpret_cast<const float4*>(bias)[2 * gl + 1];
            float v0 = fmaxf(f0.x + b0.x, 0.f), v1 = fmaxf(f0.y + b0.y, 0.f);
            float v2 = fmaxf(f1.x + b0.z, 0.f), v3 = fmaxf(f1.y + b0.w, 0.f);
            float v4 = fmaxf(f2.x + b1.x, 0.f), v5 = fmaxf(f2.y + b1.y, 0.f);
            float v6 = fmaxf(f3.x + b1.z, 0.f), v7 = fmaxf(f3.y + b1.w, 0.f);
            union { __half2 h2[4]; uint4 u; } pk;
            pk.h2[0] = __floats2half2_rn(v0, v1);
            pk.h2[1] = __floats2half2_rn(v2, v3);
            pk.h2[2] = __floats2half2_rn(v4, v5);
            pk.h2[3] = __floats2half2_rn(v6, v7);
            *reinterpret_cast<uint4*>(reinterpret_cast<__half*>(outp) + (size_t)d * C + 8 * gl) = pk.u;
        }
    } else {
        float v[8];
        float mm = -1e30f;
        if (valid) {
            const float4 b0 = reinterpret_cast<const float4*>(bias)[2 * gl];
            const float4 b1 = reinterpret_cast<const float4*>(bias)[2 * gl + 1];
            v[0] = f0.x + b0.x; v[1] = f0.y + b0.y; v[2] = f1.x + b0.z; v[3] = f1.y + b0.w;
            v[4] = f2.x + b1.x; v[5] = f2.y + b1.y; v[6] = f3.x + b1.z; v[7] = f3.y + b1.w;
#pragma unroll
            for (int j = 0; j < 8; j++) mm = fmaxf(mm, v[j]);
        }
#pragma unroll
        for (int o = 1; o <= 4; o <<= 1) mm = fmaxf(mm, __shfl_xor(mm, o));
        float ex = 0.f;
        if (valid) {
#pragma unroll
            for (int j = 0; j < 8; j++) ex += __expf(v[j] - mm);
        }
#pragma unroll
        for (int o = 1; o <= 4; o <<= 1) ex += __shfl_xor(ex, o);
        if (valid) {
            float lse = mm + logf(ex);
            float4 o0v, o1v;
            o0v.x = v[0] - lse; o0v.y = v[1] - lse; o0v.z = v[2] - lse; o0v.w = v[3] - lse;
            o1v.x = v[4] - lse; o1v.y = v[5] - lse; o1v.z = v[6] - lse; o1v.w = v[7] - lse;
            float* orow = reinterpret_cast<float*>(outp) + (size_t)d * C + 8 * gl;
            *reinterpret_cast<float4*>(orow) = o0v;
            *reinterpret_cast<float4*>(orow + 4) = o1v;
        }
    }
}

extern "C" void kernel_launch(void* const* d_in, const int* in_sizes, int n_in,
                              void* d_out, int out_size, void* d_ws, size_t ws_size,
                              hipStream_t stream) {
    const float* x   = (const float*)d_in[0];
    const int*   ei  = (const int*)d_in[1];
    const float* W1  = (const float*)d_in[2];
    const float* as1 = (const float*)d_in[3];
    const float* ad1 = (const float*)d_in[4];
    const float* b1  = (const float*)d_in[5];
    const float* W2  = (const float*)d_in[6];
    const float* as2 = (const float*)d_in[7];
    const float* ad2 = (const float*)d_in[8];
    const float* b2  = (const float*)d_in[9];
    float* out = (float*)d_out;

    char* p = (char*)d_ws;
    auto alloc = [&](size_t bytes) { void* r = p; p += (bytes + 63) & ~(size_t)63; return r; };

    size_t r0 = (size_t)N_NODES * 64 * sizeof(__half);
    size_t buckBytes = (size_t)NBUCK * BCAP * sizeof(int);
    void* region0 = alloc(r0 > buckBytes ? r0 : buckBytes);
    __half* h16 = (__half*)region0;
    int* buck   = (int*)region0;

    __half* B16 = (__half*)alloc((size_t)N_NODES * 64 * sizeof(__half));
    float* als  = (float*)alloc((size_t)N_NODES * sizeof(float));
    float* ald  = (float*)alloc((size_t)N_NODES * sizeof(float));
    int* off    = (int*)alloc((size_t)N_NODES * sizeof(int));
    int* deg    = (int*)alloc((size_t)N_NODES * sizeof(int));
    int* bcur   = (int*)alloc((size_t)NBUCK * 16 * sizeof(int));
    int* ssrc   = (int*)alloc((size_t)NBUCK * BCAP * sizeof(int));

    const int* srcA = ei;
    const int* dstA = ei + N_EDGESC;

    initB_kernel<<<1, 256, 0, stream>>>(bcur);
    bucket1_kernel<<<(ETOT + TILE - 1) / TILE, 256, 0, stream>>>(srcA, dstA, bcur, buck);
    bucket2_kernel<<<NBUCK, 256, 0, stream>>>(bcur, buck, ssrc, off, deg);

    gemm1_kernel<<<(N_NODES + 63) / 64, 256, 0, stream>>>(x, W1, as1, ad1, h16, als, ald);
    agg_kernel<HID, false, __half><<<(N_NODES * 64 + 255) / 256, 256, 0, stream>>>(
        off, deg, ssrc, als, ald, h16, b1, B16);

    gemm2_kernel<<<(N_NODES + 63) / 64, 256, 0, stream>>>(B16, W2, as2, ad2, h16, als, ald);
    agg_kernel<OUTC, true, float><<<(N_NODES * 64 + 255) / 256, 256, 0, stream>>>(
        off, deg, ssrc, als, ald, h16, b2, out);
}